// Round 11
// baseline (678.211 us; speedup 1.0000x reference)
//
#include <hip/hip_runtime.h>
#include <hip/hip_bf16.h>

#define N_NODES 10000
#define N_PAD 10112   // 79 * 128
#define N_EDGES 160000
#define N_GRAPHS 64
#define EPS 1e-5f

typedef __attribute__((ext_vector_type(8))) short bf16x8;
typedef __attribute__((ext_vector_type(4))) float f32x4;
typedef __attribute__((ext_vector_type(4))) unsigned short u16x4;

__device__ inline float b2f(unsigned short u) {
    return __uint_as_float(((unsigned)u) << 16);
}
__device__ inline unsigned short f2b(float f) {
    __hip_bfloat16 h = __float2bfloat16(f);
    return *(unsigned short*)&h;
}
__device__ inline float sigmoid_fast(float x) {
    return __builtin_amdgcn_rcpf(1.f + __expf(-x));
}

// ---------------- CSR build ----------------
__global__ void hist_kernel(const int* __restrict__ dst, int* __restrict__ counts, int E) {
    int e = blockIdx.x * blockDim.x + threadIdx.x;
    if (e < E) atomicAdd(&counts[dst[e]], 1);
}

__global__ void scan_kernel(const int* __restrict__ counts, int* __restrict__ offs,
                            int* __restrict__ pos, int n) {
    __shared__ int ls[1024];
    int t = threadIdx.x;
    int per = (n + 1023) / 1024;
    int st = t * per, en = min(st + per, n);
    int s = 0;
    for (int i = st; i < en; i++) s += counts[i];
    ls[t] = s;
    __syncthreads();
    for (int off = 1; off < 1024; off <<= 1) {
        int v = 0;
        if (t >= off) v = ls[t - off];
        __syncthreads();
        if (t >= off) ls[t] += v;
        __syncthreads();
    }
    int excl = (t == 0) ? 0 : ls[t - 1];
    for (int i = st; i < en; i++) {
        offs[i] = excl;
        pos[i] = excl;
        excl += counts[i];
    }
    if (t == 1023) offs[n] = ls[1023];
}

__global__ void scatter_kernel(const int* __restrict__ src, const int* __restrict__ dst,
                               int* __restrict__ pos, int* __restrict__ csr_src, int E) {
    int e = blockIdx.x * blockDim.x + threadIdx.x;
    if (e < E) {
        int p = atomicAdd(&pos[dst[e]], 1);
        csr_src[p] = src[e];
    }
}

// ---------------- cast x f32 -> packed bf16 [rb][k>>3][r128][8] ----------------
__global__ void cast_x_pack_kernel(const float* __restrict__ x, short* __restrict__ Xp,
                                   int N, int K) {
    int rb = blockIdx.x, t = blockIdx.y;
    size_t base = (size_t)rb * 128 * K + (size_t)t * 8192;
#pragma unroll
    for (int i = 0; i < 4; i++) {
        int c = i * 256 + threadIdx.x;
        int r = c >> 3, kc = c & 7;
        int row = rb * 128 + r;
        int f = t * 64 + kc * 8;
        float v[8] = {};
        if (row < N) {
            float4 a = *(const float4*)(x + (size_t)row * K + f);
            float4 b = *(const float4*)(x + (size_t)row * K + f + 4);
            v[0] = a.x; v[1] = a.y; v[2] = a.z; v[3] = a.w;
            v[4] = b.x; v[5] = b.y; v[6] = b.z; v[7] = b.w;
        }
        bf16x8 o;
#pragma unroll
        for (int j = 0; j < 8; j++) o[j] = (short)f2b(v[j]);
        *(bf16x8*)(Xp + base + ((size_t)kc * 128 + r) * 8) = o;
    }
}

// ---------------- pack weights: concatenated [4M, K] -> [cb][k>>3][rBN][8] bf16 ----------------
__global__ void pack_w_kernel(const float* __restrict__ W0, const float* __restrict__ W1,
                              const float* __restrict__ W2, const float* __restrict__ W3,
                              short* __restrict__ Wp, int K, int M, int BN_) {
    int c0 = blockIdx.x * 32;   // concatenated col (z*M + m)
    int k0 = blockIdx.y * 32;
    int z = c0 / M;
    int m0 = c0 - z * M;
    const float* W;
    switch (z) {
        case 0: W = W0; break;
        case 1: W = W1; break;
        case 2: W = W2; break;
        default: W = W3; break;
    }
    __shared__ float tile[32][33];   // [k][m]
#pragma unroll
    for (int i = 0; i < 4; i++) {
        int kk = k0 + threadIdx.y + i * 8;
        tile[threadIdx.y + i * 8][threadIdx.x] = W[(size_t)kk * M + m0 + threadIdx.x];
    }
    __syncthreads();
#pragma unroll
    for (int i = 0; i < 4; i++) {
        int cc = threadIdx.y + i * 8;   // col within tile
        int kk = threadIdx.x;           // k within tile
        int c = c0 + cc, k = k0 + kk;
        int cb = c / BN_, r = c - cb * BN_;
        int kc = k >> 3, j = k & 7;
        Wp[(size_t)cb * BN_ * K + ((size_t)kc * BN_ + r) * 8 + j] = (short)f2b(tile[kk][cc]);
    }
}

// ---------------- fused bf16 MFMA GEMM: packed, z-merged, 2-phase dbuf, BK=32 ----------------
// Xp: [rb][k>>3][r128][8]; Wp: [cb][k>>3][rBN][8]. Tile 128 x BN_, 4 waves (2x2).
// LDS: A 2x8KB + B 2x(BN_*32*2B). BN256 -> 48KB total, 3 blocks/CU.
// Loop: [vmcnt(0); barrier] [stage(next)] [ds_read+MFMA(cur)]  -> loads(t+1) fly under compute(t).
template <int BN_>
__global__ __launch_bounds__(256) void gemm_mfma_kernel(
    const short* __restrict__ Xp, const short* __restrict__ Wp,
    unsigned short* __restrict__ O0, unsigned short* __restrict__ O1,
    unsigned short* __restrict__ O2, unsigned short* __restrict__ O3,
    int N, int K, int M) {
    constexpr int NJ = BN_ / 32;     // col frags per wave (8 or 4)
    constexpr int BI = BN_ / 64;     // B stage insts per thread (4 or 2)
    constexpr int BSH = BN_ * 32;    // B shorts per buffer
    // bijective XCD swizzle (m204)
    int nwg = gridDim.x;
    int wid = blockIdx.x;
    int qq = nwg >> 3, rr = nwg & 7;
    int xcd = wid & 7, li = wid >> 3;
    int swz = (xcd < rr ? xcd * (qq + 1) : rr * (qq + 1) + (xcd - rr) * qq) + li;
    int cols = (4 * M) / BN_;
    int row_blk = swz / cols;
    int cb = swz - row_blk * cols;
    int c0 = cb * BN_;
    int z = c0 / M;
    int m0 = c0 - z * M;
    unsigned short* O;
    switch (z) {
        case 0: O = O0; break;
        case 1: O = O1; break;
        case 2: O = O2; break;
        default: O = O3; break;
    }
    const short* Bp = Wp + (size_t)cb * BN_ * K;
    const short* Ap = Xp + (size_t)row_blk * 128 * K;

    __shared__ __align__(16) short As[2][4096];   // 4kc * 128 * 8 each
    __shared__ __align__(16) short Bs[2][BSH];    // 4kc * BN_ * 8 each

    int tid = threadIdx.x;
    int wave = tid >> 6, lane = tid & 63;
    int wrow = wave >> 1, wcol = wave & 1;
    int l15 = lane & 15, lk = lane >> 4;
    int row0 = row_blk * 128;

    f32x4 acc[4][NJ] = {};

    auto stage = [&](int buf, int t) {
#pragma unroll
        for (int i = 0; i < 2; i++) {
            __builtin_amdgcn_global_load_lds(
                (const __attribute__((address_space(1))) unsigned int*)(Ap + (size_t)t * 4096 + (size_t)(i * 256 + tid) * 8),
                (__attribute__((address_space(3))) unsigned int*)(&As[buf][(i * 256 + wave * 64) * 8]),
                16, 0, 0);
        }
#pragma unroll
        for (int i = 0; i < BI; i++) {
            __builtin_amdgcn_global_load_lds(
                (const __attribute__((address_space(1))) unsigned int*)(Bp + (size_t)t * BSH + (size_t)(i * 256 + tid) * 8),
                (__attribute__((address_space(3))) unsigned int*)(&Bs[buf][(i * 256 + wave * 64) * 8]),
                16, 0, 0);
        }
    };

    int nt = K >> 5;  // K / 32
    stage(0, 0);
    int cur = 0;
    for (int t = 0; t < nt; t++) {
        asm volatile("s_waitcnt vmcnt(0)" ::: "memory");
        __builtin_amdgcn_s_barrier();           // cur ready; all waves done reading cur^1
        if (t + 1 < nt) stage(cur ^ 1, t + 1);  // loads fly under compute below

        bf16x8 a[4], b[NJ];
#pragma unroll
        for (int ii = 0; ii < 4; ii++)
            a[ii] = *(const bf16x8*)&As[cur][lk * 1024 + (wrow * 64 + ii * 16 + l15) * 8];
#pragma unroll
        for (int j = 0; j < NJ; j++)
            b[j] = *(const bf16x8*)&Bs[cur][lk * (BN_ * 8) + (wcol * (BN_ / 2) + j * 16 + l15) * 8];
#pragma unroll
        for (int ii = 0; ii < 4; ii++)
#pragma unroll
            for (int j = 0; j < NJ; j++)
                acc[ii][j] = __builtin_amdgcn_mfma_f32_16x16x32_bf16(a[ii], b[j], acc[ii][j], 0, 0, 0);
        cur ^= 1;
    }

#pragma unroll
    for (int ii = 0; ii < 4; ii++) {
#pragma unroll
        for (int r = 0; r < 4; r++) {
            int row = row0 + wrow * 64 + ii * 16 + lk * 4 + r;
            if (row < N) {
#pragma unroll
                for (int j = 0; j < NJ; j++) {
                    O[(size_t)row * M + m0 + wcol * (BN_ / 2) + j * 16 + l15] = f2b(acc[ii][j][r]);
                }
            }
        }
    }
}

// ---------------- edge aggregation: 4 waves/node, depth-1 prefetch, bf16 in, f32 out ----------------
template <int D>
__global__ __launch_bounds__(256) void edge_agg_kernel(
    const unsigned short* __restrict__ k, const unsigned short* __restrict__ q,
    const unsigned short* __restrict__ v, const unsigned short* __restrict__ s,
    const float* __restrict__ bias,
    const int* __restrict__ offs, const int* __restrict__ csr_src,
    float* __restrict__ y) {
    constexpr int FPL = D / 64;  // feats per lane: 8 (D=512) or 2 (D=128)
    int i = blockIdx.x;
    int wv = threadIdx.x >> 6, lane = threadIdx.x & 63;
    int f0 = lane * FPL;
    size_t base = (size_t)i * D;

    float kf[FPL];
    if constexpr (FPL == 8) {
        bf16x8 kk = *(const bf16x8*)(k + base + f0);
#pragma unroll
        for (int w = 0; w < 8; w++) kf[w] = b2f((unsigned short)kk[w]);
    } else {
        unsigned ku = *(const unsigned*)(k + base + f0);
        kf[0] = __uint_as_float(ku << 16);
        kf[1] = __uint_as_float(ku & 0xFFFF0000u);
    }

    float acc[FPL] = {};
    int e0 = offs[i], e1 = offs[i + 1];
    int cnt = e1 - e0;
    int per = (cnt + 3) >> 2;
    int es = e0 + wv * per;
    int ee = min(es + per, e1);

    if (es < ee) {
        if constexpr (FPL == 8) {
            size_t jb = (size_t)csr_src[es] * D + f0;
            bf16x8 qq = *(const bf16x8*)(q + jb);
            bf16x8 vv = *(const bf16x8*)(v + jb);
            for (int e = es; e < ee; e++) {
                bf16x8 qn, vn;
                if (e + 1 < ee) {
                    size_t jn = (size_t)csr_src[e + 1] * D + f0;
                    qn = *(const bf16x8*)(q + jn);
                    vn = *(const bf16x8*)(v + jn);
                }
#pragma unroll
                for (int w = 0; w < 8; w++)
                    acc[w] += sigmoid_fast(kf[w] + b2f((unsigned short)qq[w])) * b2f((unsigned short)vv[w]);
                qq = qn; vv = vn;
            }
        } else {
            size_t jb = (size_t)csr_src[es] * D + f0;
            unsigned qq = *(const unsigned*)(q + jb);
            unsigned vv = *(const unsigned*)(v + jb);
            for (int e = es; e < ee; e++) {
                unsigned qn = 0, vn = 0;
                if (e + 1 < ee) {
                    size_t jn = (size_t)csr_src[e + 1] * D + f0;
                    qn = *(const unsigned*)(q + jn);
                    vn = *(const unsigned*)(v + jn);
                }
                acc[0] += sigmoid_fast(kf[0] + __uint_as_float(qq << 16)) * __uint_as_float(vv << 16);
                acc[1] += sigmoid_fast(kf[1] + __uint_as_float(qq & 0xFFFF0000u)) * __uint_as_float(vv & 0xFFFF0000u);
                qq = qn; vv = vn;
            }
        }
    }

    __shared__ float red[3][D];
    if (wv > 0) {
#pragma unroll
        for (int w = 0; w < FPL; w++) red[wv - 1][f0 + w] = acc[w];
    }
    __syncthreads();
    if (wv == 0) {
        if constexpr (FPL == 8) {
            bf16x8 ssv = *(const bf16x8*)(s + base + f0);
#pragma unroll
            for (int w = 0; w < 8; w++) {
                float o = acc[w] + red[0][f0 + w] + red[1][f0 + w] + red[2][f0 + w] +
                          b2f((unsigned short)ssv[w]) + bias[f0 + w];
                y[base + f0 + w] = o > 0.f ? o : 0.f;
            }
        } else {
            unsigned su = *(const unsigned*)(s + base + f0);
            float2 bv = *(const float2*)(bias + f0);
            float ox = acc[0] + red[0][f0] + red[1][f0] + red[2][f0] +
                       __uint_as_float(su << 16) + bv.x;
            float oy = acc[1] + red[0][f0 + 1] + red[1][f0 + 1] + red[2][f0 + 1] +
                       __uint_as_float(su & 0xFFFF0000u) + bv.y;
            float2 o;
            o.x = ox > 0.f ? ox : 0.f;
            o.y = oy > 0.f ? oy : 0.f;
            *(float2*)(y + base + f0) = o;
        }
    }
}

// ---------------- batchnorm statistics (f32 input) ----------------
__global__ void col_stats_kernel(const float* __restrict__ y, int N, int D,
                                 float* __restrict__ sums, float* __restrict__ sumsq) {
    int f = blockIdx.x * 64 + (threadIdx.x & 63);
    int r0 = threadIdx.x >> 6;
    int rows_per = (N + gridDim.y - 1) / gridDim.y;
    int rs = blockIdx.y * rows_per;
    int re = min(rs + rows_per, N);
    float s = 0.f, s2 = 0.f;
    for (int r = rs + r0; r < re; r += 4) {
        float vv = y[(size_t)r * D + f];
        s += vv;
        s2 += vv * vv;
    }
    __shared__ float ls[2][256];
    ls[0][threadIdx.x] = s;
    ls[1][threadIdx.x] = s2;
    __syncthreads();
    if (threadIdx.x < 64) {
        float a = ls[0][threadIdx.x] + ls[0][threadIdx.x + 64] + ls[0][threadIdx.x + 128] + ls[0][threadIdx.x + 192];
        float b = ls[1][threadIdx.x] + ls[1][threadIdx.x + 64] + ls[1][threadIdx.x + 128] + ls[1][threadIdx.x + 192];
        atomicAdd(&sums[f], a);
        atomicAdd(&sumsq[f], b);
    }
}

// ---------------- batchnorm normalize + cast + PACK to next layer's A layout ----------------
__global__ void bn_norm_pack_kernel(const float* __restrict__ y, const float* __restrict__ sums,
                                    const float* __restrict__ sumsq, const float* __restrict__ g,
                                    const float* __restrict__ be, short* __restrict__ Xp,
                                    int N, int D, float inv_n) {
    int rb = blockIdx.x, t = blockIdx.y;
    size_t base = (size_t)rb * 128 * D + (size_t)t * 8192;
#pragma unroll
    for (int i = 0; i < 4; i++) {
        int c = i * 256 + threadIdx.x;
        int r = c >> 3, kc = c & 7;
        int row = rb * 128 + r;
        int f = t * 64 + kc * 8;
        float v[8] = {};
        if (row < N) {
            float4 a = *(const float4*)(y + (size_t)row * D + f);
            float4 b = *(const float4*)(y + (size_t)row * D + f + 4);
            v[0] = a.x; v[1] = a.y; v[2] = a.z; v[3] = a.w;
            v[4] = b.x; v[5] = b.y; v[6] = b.z; v[7] = b.w;
        }
        float4 sm0 = *(const float4*)(sums + f), sm1 = *(const float4*)(sums + f + 4);
        float4 sq0 = *(const float4*)(sumsq + f), sq1 = *(const float4*)(sumsq + f + 4);
        float4 g0 = *(const float4*)(g + f), g1 = *(const float4*)(g + f + 4);
        float4 b0 = *(const float4*)(be + f), b1 = *(const float4*)(be + f + 4);
        float sm[8] = {sm0.x, sm0.y, sm0.z, sm0.w, sm1.x, sm1.y, sm1.z, sm1.w};
        float sq[8] = {sq0.x, sq0.y, sq0.z, sq0.w, sq1.x, sq1.y, sq1.z, sq1.w};
        float gg[8] = {g0.x, g0.y, g0.z, g0.w, g1.x, g1.y, g1.z, g1.w};
        float bb[8] = {b0.x, b0.y, b0.z, b0.w, b1.x, b1.y, b1.z, b1.w};
        bf16x8 o;
#pragma unroll
        for (int j = 0; j < 8; j++) {
            float mu = sm[j] * inv_n;
            float var = sq[j] * inv_n - mu * mu;
            float val = (v[j] - mu) * rsqrtf(var + EPS) * gg[j] + bb[j];
            o[j] = (short)f2b(val);
        }
        *(bf16x8*)(Xp + base + ((size_t)kc * 128 + r) * 8) = o;
    }
}

// ---------------- last-layer batchnorm normalize fused with global add pool (f32 y) ----------------
__global__ void bn_norm_pool_kernel(const float* __restrict__ y, const float* __restrict__ sums,
                                    const float* __restrict__ sumsq, const float* __restrict__ g,
                                    const float* __restrict__ be, const int* __restrict__ batch,
                                    float* __restrict__ out, int N, int D) {
    int idx = blockIdx.x * blockDim.x + threadIdx.x;
    int total = N * D;
    float inv_n = 1.f / (float)N;
    if (idx < total) {
        int f = idx & (D - 1);
        int i = idx >> 7;  // D == 128
        float mu = sums[f] * inv_n;
        float var = sumsq[f] * inv_n - mu * mu;
        float inv = rsqrtf(var + EPS);
        float val = (y[idx] - mu) * inv * g[f] + be[f];
        atomicAdd(&out[batch[i] * D + f], val);
    }
}

extern "C" void kernel_launch(void* const* d_in, const int* in_sizes, int n_in,
                              void* d_out, int out_size, void* d_ws, size_t ws_size,
                              hipStream_t stream) {
    const float* x_in = (const float*)d_in[0];
    const int* eidx = (const int*)d_in[1];
    const int* batch = (const int*)d_in[2];
    const int N = N_NODES;
    const int E = N_EDGES;
    const int* src = eidx;
    const int* dstp = eidx + E;

    const float *Wk[5], *Wq[5], *Wv[5], *Ws[5], *bb[5], *gg[5], *bebe[5];
    for (int l = 0; l < 5; l++) {
        Wk[l]   = (const float*)d_in[3 + l * 7 + 0];
        Wq[l]   = (const float*)d_in[3 + l * 7 + 1];
        Wv[l]   = (const float*)d_in[3 + l * 7 + 2];
        Ws[l]   = (const float*)d_in[3 + l * 7 + 3];
        bb[l]   = (const float*)d_in[3 + l * 7 + 4];
        gg[l]   = (const float*)d_in[3 + l * 7 + 5];
        bebe[l] = (const float*)d_in[3 + l * 7 + 6];
    }
    const int dims_in[5]  = {128, 512, 512, 128, 128};
    const int dims_out[5] = {512, 512, 128, 128, 128};

    // ---- workspace carve ----
    char* w = (char*)d_ws;
    const size_t SZH = (size_t)N * 512 * sizeof(short);       // 10.24 MB
    unsigned short* kb16 = (unsigned short*)w; w += SZH;
    unsigned short* qb16 = (unsigned short*)w; w += SZH;
    unsigned short* vb16 = (unsigned short*)w; w += SZH;
    unsigned short* sb16 = (unsigned short*)w; w += SZH;
    float* yb = (float*)w;                     w += (size_t)N * 512 * sizeof(float);
    short* Xp = (short*)w;                     w += (size_t)N_PAD * 512 * sizeof(short);
    float* bnbuf = (float*)w;                  w += 5 * 1024 * sizeof(float);
    int* counts = (int*)w;
    int* offs = counts + 10016;
    int* pos = offs + 10016;
    int* csr = pos + 10016;
    w += (3 * 10016 + N_EDGES) * sizeof(int);
    w = (char*)(((uintptr_t)w + 255) & ~(uintptr_t)255);
    short* Wp[5];
    for (int l = 0; l < 5; l++) {
        Wp[l] = (short*)w;
        w += (size_t)4 * dims_out[l] * dims_in[l] * sizeof(short);
    }

    hipMemsetAsync(counts, 0, (size_t)N * sizeof(int), stream);
    hipMemsetAsync(bnbuf, 0, 5 * 1024 * sizeof(float), stream);
    hipMemsetAsync(d_out, 0, (size_t)out_size * sizeof(float), stream);

    hist_kernel<<<(E + 255) / 256, 256, 0, stream>>>(dstp, counts, E);
    scan_kernel<<<1, 1024, 0, stream>>>(counts, offs, pos, N);
    scatter_kernel<<<(E + 255) / 256, 256, 0, stream>>>(src, dstp, pos, csr, E);

    cast_x_pack_kernel<<<dim3(N_PAD / 128, 128 / 64), 256, 0, stream>>>(x_in, Xp, N, 128);
    for (int l = 0; l < 5; l++) {
        int K = dims_in[l], M = dims_out[l];
        int BN_ = (M == 512) ? 256 : 128;
        dim3 pg((4 * M) / 32, K / 32);
        pack_w_kernel<<<pg, dim3(32, 8), 0, stream>>>(
            Wk[l], Wq[l], Wv[l], Ws[l], Wp[l], K, M, BN_);
    }

    for (int l = 0; l < 5; l++) {
        int K = dims_in[l], M = dims_out[l];
        float* bnsum = bnbuf + l * 1024;
        float* bnsq = bnsum + 512;
        if (M == 512) {
            int nwg = (N_PAD / 128) * ((4 * M) / 256);
            gemm_mfma_kernel<256><<<nwg, 256, 0, stream>>>(
                Xp, Wp[l], kb16, qb16, vb16, sb16, N, K, M);
            edge_agg_kernel<512><<<N, 256, 0, stream>>>(kb16, qb16, vb16, sb16, bb[l], offs, csr, yb);
        } else {
            int nwg = (N_PAD / 128) * ((4 * M) / 128);
            gemm_mfma_kernel<128><<<nwg, 256, 0, stream>>>(
                Xp, Wp[l], kb16, qb16, vb16, sb16, N, K, M);
            edge_agg_kernel<128><<<N, 256, 0, stream>>>(kb16, qb16, vb16, sb16, bb[l], offs, csr, yb);
        }
        dim3 gs(M / 64, 16);
        col_stats_kernel<<<gs, 256, 0, stream>>>(yb, N, M, bnsum, bnsq);
        if (l == 4)
            bn_norm_pool_kernel<<<(N * M + 255) / 256, 256, 0, stream>>>(
                yb, bnsum, bnsq, gg[l], bebe[l], batch, (float*)d_out, N, M);
        else
            bn_norm_pack_kernel<<<dim3(N_PAD / 128, M / 64), 256, 0, stream>>>(
                yb, bnsum, bnsq, gg[l], bebe[l], Xp, N, M, 1.f / (float)N);
    }
}

// Round 13
// 660.568 us; speedup vs baseline: 1.0267x; 1.0267x over previous
//
#include <hip/hip_runtime.h>
#include <hip/hip_bf16.h>

#define N_NODES 10000
#define N_PAD 10112   // 79 * 128
#define N_EDGES 160000
#define N_GRAPHS 64
#define EPS 1e-5f

typedef __attribute__((ext_vector_type(8))) short bf16x8;
typedef __attribute__((ext_vector_type(4))) float f32x4;
typedef __attribute__((ext_vector_type(4))) unsigned short u16x4;

__device__ inline float b2f(unsigned short u) {
    return __uint_as_float(((unsigned)u) << 16);
}
__device__ inline unsigned short f2b(float f) {
    __hip_bfloat16 h = __float2bfloat16(f);
    return *(unsigned short*)&h;
}
__device__ inline float sigmoid_fast(float x) {
    return __builtin_amdgcn_rcpf(1.f + __expf(-x));
}

// ---------------- CSR build ----------------
__global__ void hist_kernel(const int* __restrict__ dst, int* __restrict__ counts, int E) {
    int e = blockIdx.x * blockDim.x + threadIdx.x;
    if (e < E) atomicAdd(&counts[dst[e]], 1);
}

__global__ void scan_kernel(const int* __restrict__ counts, int* __restrict__ offs,
                            int* __restrict__ pos, int n) {
    __shared__ int ls[1024];
    int t = threadIdx.x;
    int per = (n + 1023) / 1024;
    int st = t * per, en = min(st + per, n);
    int s = 0;
    for (int i = st; i < en; i++) s += counts[i];
    ls[t] = s;
    __syncthreads();
    for (int off = 1; off < 1024; off <<= 1) {
        int v = 0;
        if (t >= off) v = ls[t - off];
        __syncthreads();
        if (t >= off) ls[t] += v;
        __syncthreads();
    }
    int excl = (t == 0) ? 0 : ls[t - 1];
    for (int i = st; i < en; i++) {
        offs[i] = excl;
        pos[i] = excl;
        excl += counts[i];
    }
    if (t == 1023) offs[n] = ls[1023];
}

__global__ void scatter_kernel(const int* __restrict__ src, const int* __restrict__ dst,
                               int* __restrict__ pos, int* __restrict__ csr_src, int E) {
    int e = blockIdx.x * blockDim.x + threadIdx.x;
    if (e < E) {
        int p = atomicAdd(&pos[dst[e]], 1);
        csr_src[p] = src[e];
    }
}

// ---------------- cast x f32 -> packed bf16 [rb][k>>3][r128][8] ----------------
__global__ void cast_x_pack_kernel(const float* __restrict__ x, short* __restrict__ Xp,
                                   int N, int K) {
    int rb = blockIdx.x, t = blockIdx.y;
    size_t base = (size_t)rb * 128 * K + (size_t)t * 8192;
#pragma unroll
    for (int i = 0; i < 4; i++) {
        int c = i * 256 + threadIdx.x;
        int r = c >> 3, kc = c & 7;
        int row = rb * 128 + r;
        int f = t * 64 + kc * 8;
        float v[8] = {};
        if (row < N) {
            float4 a = *(const float4*)(x + (size_t)row * K + f);
            float4 b = *(const float4*)(x + (size_t)row * K + f + 4);
            v[0] = a.x; v[1] = a.y; v[2] = a.z; v[3] = a.w;
            v[4] = b.x; v[5] = b.y; v[6] = b.z; v[7] = b.w;
        }
        bf16x8 o;
#pragma unroll
        for (int j = 0; j < 8; j++) o[j] = (short)f2b(v[j]);
        *(bf16x8*)(Xp + base + ((size_t)kc * 128 + r) * 8) = o;
    }
}

// ---------------- pack weights: concatenated [4M, K] -> [cb][k>>3][rBN][8] bf16 ----------------
__global__ void pack_w_kernel(const float* __restrict__ W0, const float* __restrict__ W1,
                              const float* __restrict__ W2, const float* __restrict__ W3,
                              short* __restrict__ Wp, int K, int M, int BN_) {
    int c0 = blockIdx.x * 32;   // concatenated col (z*M + m)
    int k0 = blockIdx.y * 32;
    int z = c0 / M;
    int m0 = c0 - z * M;
    const float* W;
    switch (z) {
        case 0: W = W0; break;
        case 1: W = W1; break;
        case 2: W = W2; break;
        default: W = W3; break;
    }
    __shared__ float tile[32][33];   // [k][m]
#pragma unroll
    for (int i = 0; i < 4; i++) {
        int kk = k0 + threadIdx.y + i * 8;
        tile[threadIdx.y + i * 8][threadIdx.x] = W[(size_t)kk * M + m0 + threadIdx.x];
    }
    __syncthreads();
#pragma unroll
    for (int i = 0; i < 4; i++) {
        int cc = threadIdx.y + i * 8;   // col within tile
        int kk = threadIdx.x;           // k within tile
        int c = c0 + cc, k = k0 + kk;
        int cb = c / BN_, r = c - cb * BN_;
        int kc = k >> 3, j = k & 7;
        Wp[(size_t)cb * BN_ * K + ((size_t)kc * BN_ + r) * 8 + j] = (short)f2b(tile[kk][cc]);
    }
}

// ---------------- K=512 path: round-9 GEMM (single-buffer, BK=64, packed, z-merged) ----------------
// Xp: [rb][k>>3][r128][8]; Wp: [cb][k>>3][rBN][8]. Tile 128 x BN_, 4 waves (2x2).
// NOTE: BN_ must divide M (col-block may not straddle two z matrices).
template <int BN_>
__global__ __launch_bounds__(256) void gemm_mfma_kernel(
    const short* __restrict__ Xp, const short* __restrict__ Wp,
    unsigned short* __restrict__ O0, unsigned short* __restrict__ O1,
    unsigned short* __restrict__ O2, unsigned short* __restrict__ O3,
    int N, int K, int M) {
    constexpr int NJ = BN_ / 32;     // col frags per wave
    constexpr int BI = BN_ / 32;     // B stage insts per thread (BK=64)
    // bijective XCD swizzle (m204)
    int nwg = gridDim.x;
    int wid = blockIdx.x;
    int qq = nwg >> 3, rr = nwg & 7;
    int xcd = wid & 7, li = wid >> 3;
    int swz = (xcd < rr ? xcd * (qq + 1) : rr * (qq + 1) + (xcd - rr) * qq) + li;
    int cols = (4 * M) / BN_;
    int row_blk = swz / cols;
    int cb = swz - row_blk * cols;
    int c0 = cb * BN_;
    int z = c0 / M;
    int m0 = c0 - z * M;
    unsigned short* O;
    switch (z) {
        case 0: O = O0; break;
        case 1: O = O1; break;
        case 2: O = O2; break;
        default: O = O3; break;
    }
    const short* Bp = Wp + (size_t)cb * BN_ * K;
    const short* Ap = Xp + (size_t)row_blk * 128 * K;

    __shared__ __align__(16) short As[8192];        // 8kc * 128 * 8
    __shared__ __align__(16) short Bs[BN_ * 64];    // 8kc * BN_ * 8

    int tid = threadIdx.x;
    int wave = tid >> 6, lane = tid & 63;
    int wrow = wave >> 1, wcol = wave & 1;
    int l15 = lane & 15, lk = lane >> 4;
    int row0 = row_blk * 128;

    f32x4 acc[4][NJ] = {};

    int nt = K >> 6;  // K / 64
    for (int t = 0; t < nt; t++) {
#pragma unroll
        for (int i = 0; i < 4; i++) {
            __builtin_amdgcn_global_load_lds(
                (const __attribute__((address_space(1))) unsigned int*)(Ap + (size_t)t * 8192 + (size_t)(i * 256 + tid) * 8),
                (__attribute__((address_space(3))) unsigned int*)(As + (i * 256 + wave * 64) * 8),
                16, 0, 0);
        }
#pragma unroll
        for (int i = 0; i < BI; i++) {
            __builtin_amdgcn_global_load_lds(
                (const __attribute__((address_space(1))) unsigned int*)(Bp + (size_t)t * (BN_ * 64) + (size_t)(i * 256 + tid) * 8),
                (__attribute__((address_space(3))) unsigned int*)(Bs + (i * 256 + wave * 64) * 8),
                16, 0, 0);
        }
        __syncthreads();

#pragma unroll 1
        for (int kh = 0; kh < 2; kh++) {
            int kc = kh * 4 + lk;
            bf16x8 a[4], b[NJ];
#pragma unroll
            for (int ii = 0; ii < 4; ii++)
                a[ii] = *(const bf16x8*)&As[kc * 1024 + (wrow * 64 + ii * 16 + l15) * 8];
#pragma unroll
            for (int j = 0; j < NJ; j++)
                b[j] = *(const bf16x8*)&Bs[kc * (BN_ * 8) + (wcol * (BN_ / 2) + j * 16 + l15) * 8];
#pragma unroll
            for (int ii = 0; ii < 4; ii++)
#pragma unroll
                for (int j = 0; j < NJ; j++)
                    acc[ii][j] = __builtin_amdgcn_mfma_f32_16x16x32_bf16(a[ii], b[j], acc[ii][j], 0, 0, 0);
        }
        __syncthreads();
    }

#pragma unroll
    for (int ii = 0; ii < 4; ii++) {
#pragma unroll
        for (int r = 0; r < 4; r++) {
            int row = row0 + wrow * 64 + ii * 16 + lk * 4 + r;
            if (row < N) {
#pragma unroll
                for (int j = 0; j < NJ; j++) {
                    O[(size_t)row * M + m0 + wcol * (BN_ / 2) + j * 16 + l15] = f2b(acc[ii][j][r]);
                }
            }
        }
    }
}

// ---------------- K=128 path: single-stage GEMM, NO K-loop (BN=128 always) ----------------
__global__ __launch_bounds__(256) void gemm_k128_kernel(
    const short* __restrict__ Xp, const short* __restrict__ Wp,
    unsigned short* __restrict__ O0, unsigned short* __restrict__ O1,
    unsigned short* __restrict__ O2, unsigned short* __restrict__ O3,
    int N, int M) {
    const int K = 128;
    const int BN_ = 128;
    // bijective XCD swizzle (m204)
    int nwg = gridDim.x;
    int wid = blockIdx.x;
    int qq = nwg >> 3, rr = nwg & 7;
    int xcd = wid & 7, li = wid >> 3;
    int swz = (xcd < rr ? xcd * (qq + 1) : rr * (qq + 1) + (xcd - rr) * qq) + li;
    int cols = (4 * M) / BN_;
    int row_blk = swz / cols;
    int cb = swz - row_blk * cols;
    int c0 = cb * BN_;
    int z = c0 / M;
    int m0 = c0 - z * M;
    unsigned short* O;
    switch (z) {
        case 0: O = O0; break;
        case 1: O = O1; break;
        case 2: O = O2; break;
        default: O = O3; break;
    }
    const short* Bp = Wp + (size_t)cb * BN_ * K;
    const short* Ap = Xp + (size_t)row_blk * 128 * K;

    __shared__ __align__(16) short As[16384];   // 16kc * 128 * 8 = 32 KB
    __shared__ __align__(16) short Bs[16384];   // 16kc * 128 * 8 = 32 KB

    int tid = threadIdx.x;
    int wave = tid >> 6, lane = tid & 63;
    int wrow = wave >> 1, wcol = wave & 1;
    int l15 = lane & 15, lk = lane >> 4;
    int row0 = row_blk * 128;

    // stage both panels (all contiguous 16B copies)
#pragma unroll
    for (int i = 0; i < 8; i++) {
        __builtin_amdgcn_global_load_lds(
            (const __attribute__((address_space(1))) unsigned int*)(Ap + (size_t)(i * 256 + tid) * 8),
            (__attribute__((address_space(3))) unsigned int*)(As + (i * 256 + wave * 64) * 8),
            16, 0, 0);
        __builtin_amdgcn_global_load_lds(
            (const __attribute__((address_space(1))) unsigned int*)(Bp + (size_t)(i * 256 + tid) * 8),
            (__attribute__((address_space(3))) unsigned int*)(Bs + (i * 256 + wave * 64) * 8),
            16, 0, 0);
    }
    __syncthreads();

    f32x4 acc[4][4] = {};
#pragma unroll 1
    for (int kg = 0; kg < 4; kg++) {            // kc groups: 0,4,8,12
        int kc = kg * 4 + lk;
        bf16x8 a[4], b[4];
#pragma unroll
        for (int ii = 0; ii < 4; ii++)
            a[ii] = *(const bf16x8*)&As[kc * 1024 + (wrow * 64 + ii * 16 + l15) * 8];
#pragma unroll
        for (int j = 0; j < 4; j++)
            b[j] = *(const bf16x8*)&Bs[kc * 1024 + (wcol * 64 + j * 16 + l15) * 8];
#pragma unroll
        for (int ii = 0; ii < 4; ii++)
#pragma unroll
            for (int j = 0; j < 4; j++)
                acc[ii][j] = __builtin_amdgcn_mfma_f32_16x16x32_bf16(a[ii], b[j], acc[ii][j], 0, 0, 0);
    }

#pragma unroll
    for (int ii = 0; ii < 4; ii++) {
#pragma unroll
        for (int r = 0; r < 4; r++) {
            int row = row0 + wrow * 64 + ii * 16 + lk * 4 + r;
            if (row < N) {
#pragma unroll
                for (int j = 0; j < 4; j++) {
                    O[(size_t)row * M + m0 + wcol * 64 + j * 16 + l15] = f2b(acc[ii][j][r]);
                }
            }
        }
    }
}

// ---------------- edge aggregation: 4 waves/node, depth-1 prefetch, bf16 in, f32 out ----------------
template <int D>
__global__ __launch_bounds__(256) void edge_agg_kernel(
    const unsigned short* __restrict__ k, const unsigned short* __restrict__ q,
    const unsigned short* __restrict__ v, const unsigned short* __restrict__ s,
    const float* __restrict__ bias,
    const int* __restrict__ offs, const int* __restrict__ csr_src,
    float* __restrict__ y) {
    constexpr int FPL = D / 64;  // feats per lane: 8 (D=512) or 2 (D=128)
    int i = blockIdx.x;
    int wv = threadIdx.x >> 6, lane = threadIdx.x & 63;
    int f0 = lane * FPL;
    size_t base = (size_t)i * D;

    float kf[FPL];
    if constexpr (FPL == 8) {
        bf16x8 kk = *(const bf16x8*)(k + base + f0);
#pragma unroll
        for (int w = 0; w < 8; w++) kf[w] = b2f((unsigned short)kk[w]);
    } else {
        unsigned ku = *(const unsigned*)(k + base + f0);
        kf[0] = __uint_as_float(ku << 16);
        kf[1] = __uint_as_float(ku & 0xFFFF0000u);
    }

    float acc[FPL] = {};
    int e0 = offs[i], e1 = offs[i + 1];
    int cnt = e1 - e0;
    int per = (cnt + 3) >> 2;
    int es = e0 + wv * per;
    int ee = min(es + per, e1);

    if (es < ee) {
        if constexpr (FPL == 8) {
            size_t jb = (size_t)csr_src[es] * D + f0;
            bf16x8 qq = *(const bf16x8*)(q + jb);
            bf16x8 vv = *(const bf16x8*)(v + jb);
            for (int e = es; e < ee; e++) {
                bf16x8 qn, vn;
                if (e + 1 < ee) {
                    size_t jn = (size_t)csr_src[e + 1] * D + f0;
                    qn = *(const bf16x8*)(q + jn);
                    vn = *(const bf16x8*)(v + jn);
                }
#pragma unroll
                for (int w = 0; w < 8; w++)
                    acc[w] += sigmoid_fast(kf[w] + b2f((unsigned short)qq[w])) * b2f((unsigned short)vv[w]);
                qq = qn; vv = vn;
            }
        } else {
            size_t jb = (size_t)csr_src[es] * D + f0;
            unsigned qq = *(const unsigned*)(q + jb);
            unsigned vv = *(const unsigned*)(v + jb);
            for (int e = es; e < ee; e++) {
                unsigned qn = 0, vn = 0;
                if (e + 1 < ee) {
                    size_t jn = (size_t)csr_src[e + 1] * D + f0;
                    qn = *(const unsigned*)(q + jn);
                    vn = *(const unsigned*)(v + jn);
                }
                acc[0] += sigmoid_fast(kf[0] + __uint_as_float(qq << 16)) * __uint_as_float(vv << 16);
                acc[1] += sigmoid_fast(kf[1] + __uint_as_float(qq & 0xFFFF0000u)) * __uint_as_float(vv & 0xFFFF0000u);
                qq = qn; vv = vn;
            }
        }
    }

    __shared__ float red[3][D];
    if (wv > 0) {
#pragma unroll
        for (int w = 0; w < FPL; w++) red[wv - 1][f0 + w] = acc[w];
    }
    __syncthreads();
    if (wv == 0) {
        if constexpr (FPL == 8) {
            bf16x8 ssv = *(const bf16x8*)(s + base + f0);
#pragma unroll
            for (int w = 0; w < 8; w++) {
                float o = acc[w] + red[0][f0 + w] + red[1][f0 + w] + red[2][f0 + w] +
                          b2f((unsigned short)ssv[w]) + bias[f0 + w];
                y[base + f0 + w] = o > 0.f ? o : 0.f;
            }
        } else {
            unsigned su = *(const unsigned*)(s + base + f0);
            float2 bv = *(const float2*)(bias + f0);
            float ox = acc[0] + red[0][f0] + red[1][f0] + red[2][f0] +
                       __uint_as_float(su << 16) + bv.x;
            float oy = acc[1] + red[0][f0 + 1] + red[1][f0 + 1] + red[2][f0 + 1] +
                       __uint_as_float(su & 0xFFFF0000u) + bv.y;
            float2 o;
            o.x = ox > 0.f ? ox : 0.f;
            o.y = oy > 0.f ? oy : 0.f;
            *(float2*)(y + base + f0) = o;
        }
    }
}

// ---------------- batchnorm statistics (f32 input) ----------------
__global__ void col_stats_kernel(const float* __restrict__ y, int N, int D,
                                 float* __restrict__ sums, float* __restrict__ sumsq) {
    int f = blockIdx.x * 64 + (threadIdx.x & 63);
    int r0 = threadIdx.x >> 6;
    int rows_per = (N + gridDim.y - 1) / gridDim.y;
    int rs = blockIdx.y * rows_per;
    int re = min(rs + rows_per, N);
    float s = 0.f, s2 = 0.f;
    for (int r = rs + r0; r < re; r += 4) {
        float vv = y[(size_t)r * D + f];
        s += vv;
        s2 += vv * vv;
    }
    __shared__ float ls[2][256];
    ls[0][threadIdx.x] = s;
    ls[1][threadIdx.x] = s2;
    __syncthreads();
    if (threadIdx.x < 64) {
        float a = ls[0][threadIdx.x] + ls[0][threadIdx.x + 64] + ls[0][threadIdx.x + 128] + ls[0][threadIdx.x + 192];
        float b = ls[1][threadIdx.x] + ls[1][threadIdx.x + 64] + ls[1][threadIdx.x + 128] + ls[1][threadIdx.x + 192];
        atomicAdd(&sums[f], a);
        atomicAdd(&sumsq[f], b);
    }
}

// ---------------- batchnorm normalize + cast + PACK to next layer's A layout ----------------
__global__ void bn_norm_pack_kernel(const float* __restrict__ y, const float* __restrict__ sums,
                                    const float* __restrict__ sumsq, const float* __restrict__ g,
                                    const float* __restrict__ be, short* __restrict__ Xp,
                                    int N, int D, float inv_n) {
    int rb = blockIdx.x, t = blockIdx.y;
    size_t base = (size_t)rb * 128 * D + (size_t)t * 8192;
#pragma unroll
    for (int i = 0; i < 4; i++) {
        int c = i * 256 + threadIdx.x;
        int r = c >> 3, kc = c & 7;
        int row = rb * 128 + r;
        int f = t * 64 + kc * 8;
        float v[8] = {};
        if (row < N) {
            float4 a = *(const float4*)(y + (size_t)row * D + f);
            float4 b = *(const float4*)(y + (size_t)row * D + f + 4);
            v[0] = a.x; v[1] = a.y; v[2] = a.z; v[3] = a.w;
            v[4] = b.x; v[5] = b.y; v[6] = b.z; v[7] = b.w;
        }
        float4 sm0 = *(const float4*)(sums + f), sm1 = *(const float4*)(sums + f + 4);
        float4 sq0 = *(const float4*)(sumsq + f), sq1 = *(const float4*)(sumsq + f + 4);
        float4 g0 = *(const float4*)(g + f), g1 = *(const float4*)(g + f + 4);
        float4 b0 = *(const float4*)(be + f), b1 = *(const float4*)(be + f + 4);
        float sm[8] = {sm0.x, sm0.y, sm0.z, sm0.w, sm1.x, sm1.y, sm1.z, sm1.w};
        float sq[8] = {sq0.x, sq0.y, sq0.z, sq0.w, sq1.x, sq1.y, sq1.z, sq1.w};
        float gg[8] = {g0.x, g0.y, g0.z, g0.w, g1.x, g1.y, g1.z, g1.w};
        float bb[8] = {b0.x, b0.y, b0.z, b0.w, b1.x, b1.y, b1.z, b1.w};
        bf16x8 o;
#pragma unroll
        for (int j = 0; j < 8; j++) {
            float mu = sm[j] * inv_n;
            float var = sq[j] * inv_n - mu * mu;
            float val = (v[j] - mu) * rsqrtf(var + EPS) * gg[j] + bb[j];
            o[j] = (short)f2b(val);
        }
        *(bf16x8*)(Xp + base + ((size_t)kc * 128 + r) * 8) = o;
    }
}

// ---------------- last-layer batchnorm normalize fused with global add pool (f32 y) ----------------
__global__ void bn_norm_pool_kernel(const float* __restrict__ y, const float* __restrict__ sums,
                                    const float* __restrict__ sumsq, const float* __restrict__ g,
                                    const float* __restrict__ be, const int* __restrict__ batch,
                                    float* __restrict__ out, int N, int D) {
    int idx = blockIdx.x * blockDim.x + threadIdx.x;
    int total = N * D;
    float inv_n = 1.f / (float)N;
    if (idx < total) {
        int f = idx & (D - 1);
        int i = idx >> 7;  // D == 128
        float mu = sums[f] * inv_n;
        float var = sumsq[f] * inv_n - mu * mu;
        float inv = rsqrtf(var + EPS);
        float val = (y[idx] - mu) * inv * g[f] + be[f];
        atomicAdd(&out[batch[i] * D + f], val);
    }
}

extern "C" void kernel_launch(void* const* d_in, const int* in_sizes, int n_in,
                              void* d_out, int out_size, void* d_ws, size_t ws_size,
                              hipStream_t stream) {
    const float* x_in = (const float*)d_in[0];
    const int* eidx = (const int*)d_in[1];
    const int* batch = (const int*)d_in[2];
    const int N = N_NODES;
    const int E = N_EDGES;
    const int* src = eidx;
    const int* dstp = eidx + E;

    const float *Wk[5], *Wq[5], *Wv[5], *Ws[5], *bb[5], *gg[5], *bebe[5];
    for (int l = 0; l < 5; l++) {
        Wk[l]   = (const float*)d_in[3 + l * 7 + 0];
        Wq[l]   = (const float*)d_in[3 + l * 7 + 1];
        Wv[l]   = (const float*)d_in[3 + l * 7 + 2];
        Ws[l]   = (const float*)d_in[3 + l * 7 + 3];
        bb[l]   = (const float*)d_in[3 + l * 7 + 4];
        gg[l]   = (const float*)d_in[3 + l * 7 + 5];
        bebe[l] = (const float*)d_in[3 + l * 7 + 6];
    }
    const int dims_in[5]  = {128, 512, 512, 128, 128};
    const int dims_out[5] = {512, 512, 128, 128, 128};

    // ---- workspace carve ----
    char* w = (char*)d_ws;
    const size_t SZH = (size_t)N * 512 * sizeof(short);       // 10.24 MB
    unsigned short* kb16 = (unsigned short*)w; w += SZH;
    unsigned short* qb16 = (unsigned short*)w; w += SZH;
    unsigned short* vb16 = (unsigned short*)w; w += SZH;
    unsigned short* sb16 = (unsigned short*)w; w += SZH;
    float* yb = (float*)w;                     w += (size_t)N * 512 * sizeof(float);
    short* Xp = (short*)w;                     w += (size_t)N_PAD * 512 * sizeof(short);
    float* bnbuf = (float*)w;                  w += 5 * 1024 * sizeof(float);
    int* counts = (int*)w;
    int* offs = counts + 10016;
    int* pos = offs + 10016;
    int* csr = pos + 10016;
    w += (3 * 10016 + N_EDGES) * sizeof(int);
    w = (char*)(((uintptr_t)w + 255) & ~(uintptr_t)255);
    short* Wp[5];
    for (int l = 0; l < 5; l++) {
        Wp[l] = (short*)w;
        w += (size_t)4 * dims_out[l] * dims_in[l] * sizeof(short);
    }

    hipMemsetAsync(counts, 0, (size_t)N * sizeof(int), stream);
    hipMemsetAsync(bnbuf, 0, 5 * 1024 * sizeof(float), stream);
    hipMemsetAsync(d_out, 0, (size_t)out_size * sizeof(float), stream);

    hist_kernel<<<(E + 255) / 256, 256, 0, stream>>>(dstp, counts, E);
    scan_kernel<<<1, 1024, 0, stream>>>(counts, offs, pos, N);
    scatter_kernel<<<(E + 255) / 256, 256, 0, stream>>>(src, dstp, pos, csr, E);

    cast_x_pack_kernel<<<dim3(N_PAD / 128, 128 / 64), 256, 0, stream>>>(x_in, Xp, N, 128);
    for (int l = 0; l < 5; l++) {
        int K = dims_in[l], M = dims_out[l];
        // BN must divide M (col-block can't straddle two z matrices). 256 only for K=512,M=512.
        int BN_ = (K == 512 && M == 512) ? 256 : 128;
        dim3 pg((4 * M) / 32, K / 32);
        pack_w_kernel<<<pg, dim3(32, 8), 0, stream>>>(
            Wk[l], Wq[l], Wv[l], Ws[l], Wp[l], K, M, BN_);
    }

    for (int l = 0; l < 5; l++) {
        int K = dims_in[l], M = dims_out[l];
        float* bnsum = bnbuf + l * 1024;
        float* bnsq = bnsum + 512;
        if (K == 512) {
            if (M == 512) {
                int nwg = (N_PAD / 128) * ((4 * M) / 256);
                gemm_mfma_kernel<256><<<nwg, 256, 0, stream>>>(
                    Xp, Wp[l], kb16, qb16, vb16, sb16, N, K, M);
            } else {
                int nwg = (N_PAD / 128) * ((4 * M) / 128);
                gemm_mfma_kernel<128><<<nwg, 256, 0, stream>>>(
                    Xp, Wp[l], kb16, qb16, vb16, sb16, N, K, M);
            }
        } else {
            int nwg = (N_PAD / 128) * ((4 * M) / 128);
            gemm_k128_kernel<<<nwg, 256, 0, stream>>>(
                Xp, Wp[l], kb16, qb16, vb16, sb16, N, M);
        }
        if (M == 512)
            edge_agg_kernel<512><<<N, 256, 0, stream>>>(kb16, qb16, vb16, sb16, bb[l], offs, csr, yb);
        else
            edge_agg_kernel<128><<<N, 256, 0, stream>>>(kb16, qb16, vb16, sb16, bb[l], offs, csr, yb);
        dim3 gs(M / 64, 16);
        col_stats_kernel<<<gs, 256, 0, stream>>>(yb, N, M, bnsum, bnsq);
        if (l == 4)
            bn_norm_pool_kernel<<<(N * M + 255) / 256, 256, 0, stream>>>(
                yb, bnsum, bnsq, gg[l], bebe[l], batch, (float*)d_out, N, M);
        else
            bn_norm_pack_kernel<<<dim3(N_PAD / 128, M / 64), 256, 0, stream>>>(
                yb, bnsum, bnsq, gg[l], bebe[l], Xp, N, M, 1.f / (float)N);
    }
}

// Round 14
// 506.374 us; speedup vs baseline: 1.3393x; 1.3045x over previous
//
#include <hip/hip_runtime.h>
#include <hip/hip_bf16.h>

#define N_NODES 10000
#define N_PAD 10112   // 79 * 128
#define N_EDGES 160000
#define N_GRAPHS 64
#define EPS 1e-5f

typedef __attribute__((ext_vector_type(8))) short bf16x8;
typedef __attribute__((ext_vector_type(4))) float f32x4;
typedef __attribute__((ext_vector_type(4))) unsigned short u16x4;

__device__ inline float b2f(unsigned short u) {
    return __uint_as_float(((unsigned)u) << 16);
}
__device__ inline unsigned short f2b(float f) {
    __hip_bfloat16 h = __float2bfloat16(f);
    return *(unsigned short*)&h;
}
__device__ inline float sigmoid_fast(float x) {
    return __builtin_amdgcn_rcpf(1.f + __expf(-x));
}

// ---------------- CSR build ----------------
__global__ void hist_kernel(const int* __restrict__ dst, int* __restrict__ counts, int E) {
    int e = blockIdx.x * blockDim.x + threadIdx.x;
    if (e < E) atomicAdd(&counts[dst[e]], 1);
}

__global__ void scan_kernel(const int* __restrict__ counts, int* __restrict__ offs,
                            int* __restrict__ pos, int n) {
    __shared__ int ls[1024];
    int t = threadIdx.x;
    int per = (n + 1023) / 1024;
    int st = t * per, en = min(st + per, n);
    int s = 0;
    for (int i = st; i < en; i++) s += counts[i];
    ls[t] = s;
    __syncthreads();
    for (int off = 1; off < 1024; off <<= 1) {
        int v = 0;
        if (t >= off) v = ls[t - off];
        __syncthreads();
        if (t >= off) ls[t] += v;
        __syncthreads();
    }
    int excl = (t == 0) ? 0 : ls[t - 1];
    for (int i = st; i < en; i++) {
        offs[i] = excl;
        pos[i] = excl;
        excl += counts[i];
    }
    if (t == 1023) offs[n] = ls[1023];
}

__global__ void scatter_kernel(const int* __restrict__ src, const int* __restrict__ dst,
                               int* __restrict__ pos, int* __restrict__ csr_src, int E) {
    int e = blockIdx.x * blockDim.x + threadIdx.x;
    if (e < E) {
        int p = atomicAdd(&pos[dst[e]], 1);
        csr_src[p] = src[e];
    }
}

// ---------------- cast x f32 -> packed bf16 [rb][k>>3][r128][8] ----------------
__global__ void cast_x_pack_kernel(const float* __restrict__ x, short* __restrict__ Xp,
                                   int N, int K) {
    int rb = blockIdx.x, t = blockIdx.y;
    size_t base = (size_t)rb * 128 * K + (size_t)t * 8192;
#pragma unroll
    for (int i = 0; i < 4; i++) {
        int c = i * 256 + threadIdx.x;
        int r = c >> 3, kc = c & 7;
        int row = rb * 128 + r;
        int f = t * 64 + kc * 8;
        float v[8] = {};
        if (row < N) {
            float4 a = *(const float4*)(x + (size_t)row * K + f);
            float4 b = *(const float4*)(x + (size_t)row * K + f + 4);
            v[0] = a.x; v[1] = a.y; v[2] = a.z; v[3] = a.w;
            v[4] = b.x; v[5] = b.y; v[6] = b.z; v[7] = b.w;
        }
        bf16x8 o;
#pragma unroll
        for (int j = 0; j < 8; j++) o[j] = (short)f2b(v[j]);
        *(bf16x8*)(Xp + base + ((size_t)kc * 128 + r) * 8) = o;
    }
}

// ---------------- pack weights: concatenated [4M, K] -> [cb][k>>3][rBN][8] bf16 ----------------
__global__ void pack_w_kernel(const float* __restrict__ W0, const float* __restrict__ W1,
                              const float* __restrict__ W2, const float* __restrict__ W3,
                              short* __restrict__ Wp, int K, int M, int BN_) {
    int c0 = blockIdx.x * 32;   // concatenated col (z*M + m)
    int k0 = blockIdx.y * 32;
    int z = c0 / M;
    int m0 = c0 - z * M;
    const float* W;
    switch (z) {
        case 0: W = W0; break;
        case 1: W = W1; break;
        case 2: W = W2; break;
        default: W = W3; break;
    }
    __shared__ float tile[32][33];   // [k][m]
#pragma unroll
    for (int i = 0; i < 4; i++) {
        int kk = k0 + threadIdx.y + i * 8;
        tile[threadIdx.y + i * 8][threadIdx.x] = W[(size_t)kk * M + m0 + threadIdx.x];
    }
    __syncthreads();
#pragma unroll
    for (int i = 0; i < 4; i++) {
        int cc = threadIdx.y + i * 8;   // col within tile
        int kk = threadIdx.x;           // k within tile
        int c = c0 + cc, k = k0 + kk;
        int cb = c / BN_, r = c - cb * BN_;
        int kc = k >> 3, j = k & 7;
        Wp[(size_t)cb * BN_ * K + ((size_t)kc * BN_ + r) * 8 + j] = (short)f2b(tile[kk][cc]);
    }
}

// ---------------- K=512 path: single-buffer BK=64 GEMM (packed, z-merged) ----------------
template <int BN_>
__global__ __launch_bounds__(256) void gemm_mfma_kernel(
    const short* __restrict__ Xp, const short* __restrict__ Wp,
    unsigned short* __restrict__ O0, unsigned short* __restrict__ O1,
    unsigned short* __restrict__ O2, unsigned short* __restrict__ O3,
    int N, int K, int M) {
    constexpr int NJ = BN_ / 32;
    constexpr int BI = BN_ / 32;
    // bijective XCD swizzle (m204)
    int nwg = gridDim.x;
    int wid = blockIdx.x;
    int qq = nwg >> 3, rr = nwg & 7;
    int xcd = wid & 7, li = wid >> 3;
    int swz = (xcd < rr ? xcd * (qq + 1) : rr * (qq + 1) + (xcd - rr) * qq) + li;
    int cols = (4 * M) / BN_;
    int row_blk = swz / cols;
    int cb = swz - row_blk * cols;
    int c0 = cb * BN_;
    int z = c0 / M;
    int m0 = c0 - z * M;
    unsigned short* O;
    switch (z) {
        case 0: O = O0; break;
        case 1: O = O1; break;
        case 2: O = O2; break;
        default: O = O3; break;
    }
    const short* Bp = Wp + (size_t)cb * BN_ * K;
    const short* Ap = Xp + (size_t)row_blk * 128 * K;

    __shared__ __align__(16) short As[8192];
    __shared__ __align__(16) short Bs[BN_ * 64];

    int tid = threadIdx.x;
    int wave = tid >> 6, lane = tid & 63;
    int wrow = wave >> 1, wcol = wave & 1;
    int l15 = lane & 15, lk = lane >> 4;
    int row0 = row_blk * 128;

    f32x4 acc[4][NJ] = {};

    int nt = K >> 6;
    for (int t = 0; t < nt; t++) {
#pragma unroll
        for (int i = 0; i < 4; i++) {
            __builtin_amdgcn_global_load_lds(
                (const __attribute__((address_space(1))) unsigned int*)(Ap + (size_t)t * 8192 + (size_t)(i * 256 + tid) * 8),
                (__attribute__((address_space(3))) unsigned int*)(As + (i * 256 + wave * 64) * 8),
                16, 0, 0);
        }
#pragma unroll
        for (int i = 0; i < BI; i++) {
            __builtin_amdgcn_global_load_lds(
                (const __attribute__((address_space(1))) unsigned int*)(Bp + (size_t)t * (BN_ * 64) + (size_t)(i * 256 + tid) * 8),
                (__attribute__((address_space(3))) unsigned int*)(Bs + (i * 256 + wave * 64) * 8),
                16, 0, 0);
        }
        __syncthreads();

#pragma unroll 1
        for (int kh = 0; kh < 2; kh++) {
            int kc = kh * 4 + lk;
            bf16x8 a[4], b[NJ];
#pragma unroll
            for (int ii = 0; ii < 4; ii++)
                a[ii] = *(const bf16x8*)&As[kc * 1024 + (wrow * 64 + ii * 16 + l15) * 8];
#pragma unroll
            for (int j = 0; j < NJ; j++)
                b[j] = *(const bf16x8*)&Bs[kc * (BN_ * 8) + (wcol * (BN_ / 2) + j * 16 + l15) * 8];
#pragma unroll
            for (int ii = 0; ii < 4; ii++)
#pragma unroll
                for (int j = 0; j < NJ; j++)
                    acc[ii][j] = __builtin_amdgcn_mfma_f32_16x16x32_bf16(a[ii], b[j], acc[ii][j], 0, 0, 0);
        }
        __syncthreads();
    }

#pragma unroll
    for (int ii = 0; ii < 4; ii++) {
#pragma unroll
        for (int r = 0; r < 4; r++) {
            int row = row0 + wrow * 64 + ii * 16 + lk * 4 + r;
            if (row < N) {
#pragma unroll
                for (int j = 0; j < NJ; j++) {
                    O[(size_t)row * M + m0 + wcol * (BN_ / 2) + j * 16 + l15] = f2b(acc[ii][j][r]);
                }
            }
        }
    }
}

// ---------------- K=128 path: single-stage GEMM, NO K-loop (BN=128 always) ----------------
__global__ __launch_bounds__(256) void gemm_k128_kernel(
    const short* __restrict__ Xp, const short* __restrict__ Wp,
    unsigned short* __restrict__ O0, unsigned short* __restrict__ O1,
    unsigned short* __restrict__ O2, unsigned short* __restrict__ O3,
    int N, int M) {
    const int K = 128;
    const int BN_ = 128;
    int nwg = gridDim.x;
    int wid = blockIdx.x;
    int qq = nwg >> 3, rr = nwg & 7;
    int xcd = wid & 7, li = wid >> 3;
    int swz = (xcd < rr ? xcd * (qq + 1) : rr * (qq + 1) + (xcd - rr) * qq) + li;
    int cols = (4 * M) / BN_;
    int row_blk = swz / cols;
    int cb = swz - row_blk * cols;
    int c0 = cb * BN_;
    int z = c0 / M;
    int m0 = c0 - z * M;
    unsigned short* O;
    switch (z) {
        case 0: O = O0; break;
        case 1: O = O1; break;
        case 2: O = O2; break;
        default: O = O3; break;
    }
    const short* Bp = Wp + (size_t)cb * BN_ * K;
    const short* Ap = Xp + (size_t)row_blk * 128 * K;

    __shared__ __align__(16) short As[16384];
    __shared__ __align__(16) short Bs[16384];

    int tid = threadIdx.x;
    int wave = tid >> 6, lane = tid & 63;
    int wrow = wave >> 1, wcol = wave & 1;
    int l15 = lane & 15, lk = lane >> 4;
    int row0 = row_blk * 128;

#pragma unroll
    for (int i = 0; i < 8; i++) {
        __builtin_amdgcn_global_load_lds(
            (const __attribute__((address_space(1))) unsigned int*)(Ap + (size_t)(i * 256 + tid) * 8),
            (__attribute__((address_space(3))) unsigned int*)(As + (i * 256 + wave * 64) * 8),
            16, 0, 0);
        __builtin_amdgcn_global_load_lds(
            (const __attribute__((address_space(1))) unsigned int*)(Bp + (size_t)(i * 256 + tid) * 8),
            (__attribute__((address_space(3))) unsigned int*)(Bs + (i * 256 + wave * 64) * 8),
            16, 0, 0);
    }
    __syncthreads();

    f32x4 acc[4][4] = {};
#pragma unroll 1
    for (int kg = 0; kg < 4; kg++) {
        int kc = kg * 4 + lk;
        bf16x8 a[4], b[4];
#pragma unroll
        for (int ii = 0; ii < 4; ii++)
            a[ii] = *(const bf16x8*)&As[kc * 1024 + (wrow * 64 + ii * 16 + l15) * 8];
#pragma unroll
        for (int j = 0; j < 4; j++)
            b[j] = *(const bf16x8*)&Bs[kc * 1024 + (wcol * 64 + j * 16 + l15) * 8];
#pragma unroll
        for (int ii = 0; ii < 4; ii++)
#pragma unroll
            for (int j = 0; j < 4; j++)
                acc[ii][j] = __builtin_amdgcn_mfma_f32_16x16x32_bf16(a[ii], b[j], acc[ii][j], 0, 0, 0);
    }

#pragma unroll
    for (int ii = 0; ii < 4; ii++) {
#pragma unroll
        for (int r = 0; r < 4; r++) {
            int row = row0 + wrow * 64 + ii * 16 + lk * 4 + r;
            if (row < N) {
#pragma unroll
                for (int j = 0; j < 4; j++) {
                    O[(size_t)row * M + m0 + wcol * 64 + j * 16 + l15] = f2b(acc[ii][j][r]);
                }
            }
        }
    }
}

// ---------------- edge aggregation: 4 waves/node, BATCHED-4 gathers (MLP 8) ----------------
template <int D>
__global__ __launch_bounds__(256) void edge_agg_kernel(
    const unsigned short* __restrict__ k, const unsigned short* __restrict__ q,
    const unsigned short* __restrict__ v, const unsigned short* __restrict__ s,
    const float* __restrict__ bias,
    const int* __restrict__ offs, const int* __restrict__ csr_src,
    float* __restrict__ y) {
    constexpr int FPL = D / 64;  // 8 (D=512) or 2 (D=128)
    int i = blockIdx.x;
    int wv = threadIdx.x >> 6, lane = threadIdx.x & 63;
    int f0 = lane * FPL;
    size_t base = (size_t)i * D;

    float kf[FPL];
    if constexpr (FPL == 8) {
        bf16x8 kk = *(const bf16x8*)(k + base + f0);
#pragma unroll
        for (int w = 0; w < 8; w++) kf[w] = b2f((unsigned short)kk[w]);
    } else {
        unsigned ku = *(const unsigned*)(k + base + f0);
        kf[0] = __uint_as_float(ku << 16);
        kf[1] = __uint_as_float(ku & 0xFFFF0000u);
    }

    float acc[FPL] = {};
    int e0 = offs[i], e1 = offs[i + 1];
    int cnt = e1 - e0;
    int per = (cnt + 3) >> 2;
    int es = e0 + wv * per;
    int ee = min(es + per, e1);

    for (int e = es; e < ee; e += 4) {
        int n = ee - e;            // wave-uniform
        if (n > 4) n = 4;
        int js[4];
#pragma unroll
        for (int u = 0; u < 4; u++) js[u] = csr_src[(u < n) ? (e + u) : e];
        if constexpr (FPL == 8) {
            bf16x8 qv[4], vv[4];
#pragma unroll
            for (int u = 0; u < 4; u++) {
                size_t jb = (size_t)js[u] * D + f0;
                qv[u] = *(const bf16x8*)(q + jb);
                vv[u] = *(const bf16x8*)(v + jb);
            }
#pragma unroll
            for (int u = 0; u < 4; u++) {
                if (u < n) {
#pragma unroll
                    for (int w = 0; w < 8; w++)
                        acc[w] += sigmoid_fast(kf[w] + b2f((unsigned short)qv[u][w])) *
                                  b2f((unsigned short)vv[u][w]);
                }
            }
        } else {
            unsigned qv[4], vv[4];
#pragma unroll
            for (int u = 0; u < 4; u++) {
                size_t jb = (size_t)js[u] * D + f0;
                qv[u] = *(const unsigned*)(q + jb);
                vv[u] = *(const unsigned*)(v + jb);
            }
#pragma unroll
            for (int u = 0; u < 4; u++) {
                if (u < n) {
                    acc[0] += sigmoid_fast(kf[0] + __uint_as_float(qv[u] << 16)) *
                              __uint_as_float(vv[u] << 16);
                    acc[1] += sigmoid_fast(kf[1] + __uint_as_float(qv[u] & 0xFFFF0000u)) *
                              __uint_as_float(vv[u] & 0xFFFF0000u);
                }
            }
        }
    }

    __shared__ float red[3][D];
    if (wv > 0) {
#pragma unroll
        for (int w = 0; w < FPL; w++) red[wv - 1][f0 + w] = acc[w];
    }
    __syncthreads();
    if (wv == 0) {
        if constexpr (FPL == 8) {
            bf16x8 ssv = *(const bf16x8*)(s + base + f0);
#pragma unroll
            for (int w = 0; w < 8; w++) {
                float o = acc[w] + red[0][f0 + w] + red[1][f0 + w] + red[2][f0 + w] +
                          b2f((unsigned short)ssv[w]) + bias[f0 + w];
                y[base + f0 + w] = o > 0.f ? o : 0.f;
            }
        } else {
            unsigned su = *(const unsigned*)(s + base + f0);
            float2 bv = *(const float2*)(bias + f0);
            float ox = acc[0] + red[0][f0] + red[1][f0] + red[2][f0] +
                       __uint_as_float(su << 16) + bv.x;
            float oy = acc[1] + red[0][f0 + 1] + red[1][f0 + 1] + red[2][f0 + 1] +
                       __uint_as_float(su & 0xFFFF0000u) + bv.y;
            float2 o;
            o.x = ox > 0.f ? ox : 0.f;
            o.y = oy > 0.f ? oy : 0.f;
            *(float2*)(y + base + f0) = o;
        }
    }
}

// ---------------- batchnorm statistics (f32 input) ----------------
__global__ void col_stats_kernel(const float* __restrict__ y, int N, int D,
                                 float* __restrict__ sums, float* __restrict__ sumsq) {
    int f = blockIdx.x * 64 + (threadIdx.x & 63);
    int r0 = threadIdx.x >> 6;
    int rows_per = (N + gridDim.y - 1) / gridDim.y;
    int rs = blockIdx.y * rows_per;
    int re = min(rs + rows_per, N);
    float s = 0.f, s2 = 0.f;
    for (int r = rs + r0; r < re; r += 4) {
        float vv = y[(size_t)r * D + f];
        s += vv;
        s2 += vv * vv;
    }
    __shared__ float ls[2][256];
    ls[0][threadIdx.x] = s;
    ls[1][threadIdx.x] = s2;
    __syncthreads();
    if (threadIdx.x < 64) {
        float a = ls[0][threadIdx.x] + ls[0][threadIdx.x + 64] + ls[0][threadIdx.x + 128] + ls[0][threadIdx.x + 192];
        float b = ls[1][threadIdx.x] + ls[1][threadIdx.x + 64] + ls[1][threadIdx.x + 128] + ls[1][threadIdx.x + 192];
        atomicAdd(&sums[f], a);
        atomicAdd(&sumsq[f], b);
    }
}

// ---------------- batchnorm normalize + cast + PACK to next layer's A layout ----------------
__global__ void bn_norm_pack_kernel(const float* __restrict__ y, const float* __restrict__ sums,
                                    const float* __restrict__ sumsq, const float* __restrict__ g,
                                    const float* __restrict__ be, short* __restrict__ Xp,
                                    int N, int D, float inv_n) {
    int rb = blockIdx.x, t = blockIdx.y;
    size_t base = (size_t)rb * 128 * D + (size_t)t * 8192;
#pragma unroll
    for (int i = 0; i < 4; i++) {
        int c = i * 256 + threadIdx.x;
        int r = c >> 3, kc = c & 7;
        int row = rb * 128 + r;
        int f = t * 64 + kc * 8;
        float v[8] = {};
        if (row < N) {
            float4 a = *(const float4*)(y + (size_t)row * D + f);
            float4 b = *(const float4*)(y + (size_t)row * D + f + 4);
            v[0] = a.x; v[1] = a.y; v[2] = a.z; v[3] = a.w;
            v[4] = b.x; v[5] = b.y; v[6] = b.z; v[7] = b.w;
        }
        float4 sm0 = *(const float4*)(sums + f), sm1 = *(const float4*)(sums + f + 4);
        float4 sq0 = *(const float4*)(sumsq + f), sq1 = *(const float4*)(sumsq + f + 4);
        float4 g0 = *(const float4*)(g + f), g1 = *(const float4*)(g + f + 4);
        float4 b0 = *(const float4*)(be + f), b1 = *(const float4*)(be + f + 4);
        float sm[8] = {sm0.x, sm0.y, sm0.z, sm0.w, sm1.x, sm1.y, sm1.z, sm1.w};
        float sq[8] = {sq0.x, sq0.y, sq0.z, sq0.w, sq1.x, sq1.y, sq1.z, sq1.w};
        float gg[8] = {g0.x, g0.y, g0.z, g0.w, g1.x, g1.y, g1.z, g1.w};
        float bb[8] = {b0.x, b0.y, b0.z, b0.w, b1.x, b1.y, b1.z, b1.w};
        bf16x8 o;
#pragma unroll
        for (int j = 0; j < 8; j++) {
            float mu = sm[j] * inv_n;
            float var = sq[j] * inv_n - mu * mu;
            float val = (v[j] - mu) * rsqrtf(var + EPS) * gg[j] + bb[j];
            o[j] = (short)f2b(val);
        }
        *(bf16x8*)(Xp + base + ((size_t)kc * 128 + r) * 8) = o;
    }
}

// ---------------- last-layer batchnorm normalize fused with global add pool (f32 y) ----------------
__global__ void bn_norm_pool_kernel(const float* __restrict__ y, const float* __restrict__ sums,
                                    const float* __restrict__ sumsq, const float* __restrict__ g,
                                    const float* __restrict__ be, const int* __restrict__ batch,
                                    float* __restrict__ out, int N, int D) {
    int idx = blockIdx.x * blockDim.x + threadIdx.x;
    int total = N * D;
    float inv_n = 1.f / (float)N;
    if (idx < total) {
        int f = idx & (D - 1);
        int i = idx >> 7;  // D == 128
        float mu = sums[f] * inv_n;
        float var = sumsq[f] * inv_n - mu * mu;
        float inv = rsqrtf(var + EPS);
        float val = (y[idx] - mu) * inv * g[f] + be[f];
        atomicAdd(&out[batch[i] * D + f], val);
    }
}

extern "C" void kernel_launch(void* const* d_in, const int* in_sizes, int n_in,
                              void* d_out, int out_size, void* d_ws, size_t ws_size,
                              hipStream_t stream) {
    const float* x_in = (const float*)d_in[0];
    const int* eidx = (const int*)d_in[1];
    const int* batch = (const int*)d_in[2];
    const int N = N_NODES;
    const int E = N_EDGES;
    const int* src = eidx;
    const int* dstp = eidx + E;

    const float *Wk[5], *Wq[5], *Wv[5], *Ws[5], *bb[5], *gg[5], *bebe[5];
    for (int l = 0; l < 5; l++) {
        Wk[l]   = (const float*)d_in[3 + l * 7 + 0];
        Wq[l]   = (const float*)d_in[3 + l * 7 + 1];
        Wv[l]   = (const float*)d_in[3 + l * 7 + 2];
        Ws[l]   = (const float*)d_in[3 + l * 7 + 3];
        bb[l]   = (const float*)d_in[3 + l * 7 + 4];
        gg[l]   = (const float*)d_in[3 + l * 7 + 5];
        bebe[l] = (const float*)d_in[3 + l * 7 + 6];
    }
    const int dims_in[5]  = {128, 512, 512, 128, 128};
    const int dims_out[5] = {512, 512, 128, 128, 128};

    // ---- workspace carve ----
    char* w = (char*)d_ws;
    const size_t SZH = (size_t)N * 512 * sizeof(short);       // 10.24 MB
    unsigned short* kb16 = (unsigned short*)w; w += SZH;
    unsigned short* qb16 = (unsigned short*)w; w += SZH;
    unsigned short* vb16 = (unsigned short*)w; w += SZH;
    unsigned short* sb16 = (unsigned short*)w; w += SZH;
    float* yb = (float*)w;                     w += (size_t)N * 512 * sizeof(float);
    short* Xp = (short*)w;                     w += (size_t)N_PAD * 512 * sizeof(short);
    float* bnbuf = (float*)w;                  w += 5 * 1024 * sizeof(float);
    int* counts = (int*)w;
    int* offs = counts + 10016;
    int* pos = offs + 10016;
    int* csr = pos + 10016;
    w += (3 * 10016 + N_EDGES) * sizeof(int);
    w = (char*)(((uintptr_t)w + 255) & ~(uintptr_t)255);
    short* Wp[5];
    for (int l = 0; l < 5; l++) {
        Wp[l] = (short*)w;
        w += (size_t)4 * dims_out[l] * dims_in[l] * sizeof(short);
    }

    hipMemsetAsync(counts, 0, (size_t)N * sizeof(int), stream);
    hipMemsetAsync(bnbuf, 0, 5 * 1024 * sizeof(float), stream);
    hipMemsetAsync(d_out, 0, (size_t)out_size * sizeof(float), stream);

    hist_kernel<<<(E + 255) / 256, 256, 0, stream>>>(dstp, counts, E);
    scan_kernel<<<1, 1024, 0, stream>>>(counts, offs, pos, N);
    scatter_kernel<<<(E + 255) / 256, 256, 0, stream>>>(src, dstp, pos, csr, E);

    cast_x_pack_kernel<<<dim3(N_PAD / 128, 128 / 64), 256, 0, stream>>>(x_in, Xp, N, 128);
    for (int l = 0; l < 5; l++) {
        int K = dims_in[l], M = dims_out[l];
        int BN_ = (K == 512 && M == 512) ? 256 : 128;
        dim3 pg((4 * M) / 32, K / 32);
        pack_w_kernel<<<pg, dim3(32, 8), 0, stream>>>(
            Wk[l], Wq[l], Wv[l], Ws[l], Wp[l], K, M, BN_);
    }

    for (int l = 0; l < 5; l++) {
        int K = dims_in[l], M = dims_out[l];
        float* bnsum = bnbuf + l * 1024;
        float* bnsq = bnsum + 512;
        if (K == 512) {
            if (M == 512) {
                int nwg = (N_PAD / 128) * ((4 * M) / 256);
                gemm_mfma_kernel<256><<<nwg, 256, 0, stream>>>(
                    Xp, Wp[l], kb16, qb16, vb16, sb16, N, K, M);
            } else {
                int nwg = (N_PAD / 128) * ((4 * M) / 128);
                gemm_mfma_kernel<128><<<nwg, 256, 0, stream>>>(
                    Xp, Wp[l], kb16, qb16, vb16, sb16, N, K, M);
            }
        } else {
            int nwg = (N_PAD / 128) * ((4 * M) / 128);
            gemm_k128_kernel<<<nwg, 256, 0, stream>>>(
                Xp, Wp[l], kb16, qb16, vb16, sb16, N, M);
        }
        if (M == 512)
            edge_agg_kernel<512><<<N, 256, 0, stream>>>(kb16, qb16, vb16, sb16, bb[l], offs, csr, yb);
        else
            edge_agg_kernel<128><<<N, 256, 0, stream>>>(kb16, qb16, vb16, sb16, bb[l], offs, csr, yb);
        dim3 gs(M / 64, 79);   // occupancy fix: 16 -> 79 row-chunks
        col_stats_kernel<<<gs, 256, 0, stream>>>(yb, N, M, bnsum, bnsq);
        if (l == 4)
            bn_norm_pool_kernel<<<(N * M + 255) / 256, 256, 0, stream>>>(
                yb, bnsum, bnsq, gg[l], bebe[l], batch, (float*)d_out, N, M);
        else
            bn_norm_pack_kernel<<<dim3(N_PAD / 128, M / 64), 256, 0, stream>>>(
                yb, bnsum, bnsq, gg[l], bebe[l], Xp, N, M, 1.f / (float)N);
    }
}

// Round 15
// 489.164 us; speedup vs baseline: 1.3865x; 1.0352x over previous
//
#include <hip/hip_runtime.h>
#include <hip/hip_bf16.h>

#define N_NODES 10000
#define N_PAD 10112   // 79 * 128
#define N_EDGES 160000
#define N_GRAPHS 64
#define EPS 1e-5f

typedef __attribute__((ext_vector_type(8))) short bf16x8;
typedef __attribute__((ext_vector_type(4))) float f32x4;
typedef __attribute__((ext_vector_type(4))) unsigned short u16x4;

__device__ inline float b2f(unsigned short u) {
    return __uint_as_float(((unsigned)u) << 16);
}
__device__ inline unsigned short f2b(float f) {
    __hip_bfloat16 h = __float2bfloat16(f);
    return *(unsigned short*)&h;
}
__device__ inline float sigmoid_fast(float x) {
    return __builtin_amdgcn_rcpf(1.f + __expf(-x));
}

// ---------------- CSR build ----------------
__global__ void hist_kernel(const int* __restrict__ dst, int* __restrict__ counts, int E) {
    int e = blockIdx.x * blockDim.x + threadIdx.x;
    if (e < E) atomicAdd(&counts[dst[e]], 1);
}

__global__ void scan_kernel(const int* __restrict__ counts, int* __restrict__ offs,
                            int* __restrict__ pos, int n) {
    __shared__ int ls[1024];
    int t = threadIdx.x;
    int per = (n + 1023) / 1024;
    int st = t * per, en = min(st + per, n);
    int s = 0;
    for (int i = st; i < en; i++) s += counts[i];
    ls[t] = s;
    __syncthreads();
    for (int off = 1; off < 1024; off <<= 1) {
        int v = 0;
        if (t >= off) v = ls[t - off];
        __syncthreads();
        if (t >= off) ls[t] += v;
        __syncthreads();
    }
    int excl = (t == 0) ? 0 : ls[t - 1];
    for (int i = st; i < en; i++) {
        offs[i] = excl;
        pos[i] = excl;
        excl += counts[i];
    }
    if (t == 1023) offs[n] = ls[1023];
}

__global__ void scatter_kernel(const int* __restrict__ src, const int* __restrict__ dst,
                               int* __restrict__ pos, int* __restrict__ csr_src, int E) {
    int e = blockIdx.x * blockDim.x + threadIdx.x;
    if (e < E) {
        int p = atomicAdd(&pos[dst[e]], 1);
        csr_src[p] = src[e];
    }
}

// ---------------- cast x f32 -> packed bf16 [rb][k>>3][r128][8] ----------------
__global__ void cast_x_pack_kernel(const float* __restrict__ x, short* __restrict__ Xp,
                                   int N, int K) {
    int rb = blockIdx.x, t = blockIdx.y;
    size_t base = (size_t)rb * 128 * K + (size_t)t * 8192;
#pragma unroll
    for (int i = 0; i < 4; i++) {
        int c = i * 256 + threadIdx.x;
        int r = c >> 3, kc = c & 7;
        int row = rb * 128 + r;
        int f = t * 64 + kc * 8;
        float v[8] = {};
        if (row < N) {
            float4 a = *(const float4*)(x + (size_t)row * K + f);
            float4 b = *(const float4*)(x + (size_t)row * K + f + 4);
            v[0] = a.x; v[1] = a.y; v[2] = a.z; v[3] = a.w;
            v[4] = b.x; v[5] = b.y; v[6] = b.z; v[7] = b.w;
        }
        bf16x8 o;
#pragma unroll
        for (int j = 0; j < 8; j++) o[j] = (short)f2b(v[j]);
        *(bf16x8*)(Xp + base + ((size_t)kc * 128 + r) * 8) = o;
    }
}

// ---------------- pack weights: concatenated [4M, K] -> [cb][k>>3][r128][8] bf16 (BN=128) ----------------
__global__ void pack_w_kernel(const float* __restrict__ W0, const float* __restrict__ W1,
                              const float* __restrict__ W2, const float* __restrict__ W3,
                              short* __restrict__ Wp, int K, int M) {
    const int BN_ = 128;
    int c0 = blockIdx.x * 32;   // concatenated col (z*M + m)
    int k0 = blockIdx.y * 32;
    int z = c0 / M;
    int m0 = c0 - z * M;
    const float* W;
    switch (z) {
        case 0: W = W0; break;
        case 1: W = W1; break;
        case 2: W = W2; break;
        default: W = W3; break;
    }
    __shared__ float tile[32][33];   // [k][m]
#pragma unroll
    for (int i = 0; i < 4; i++) {
        int kk = k0 + threadIdx.y + i * 8;
        tile[threadIdx.y + i * 8][threadIdx.x] = W[(size_t)kk * M + m0 + threadIdx.x];
    }
    __syncthreads();
#pragma unroll
    for (int i = 0; i < 4; i++) {
        int cc = threadIdx.y + i * 8;   // col within tile
        int kk = threadIdx.x;           // k within tile
        int c = c0 + cc, k = k0 + kk;
        int cb = c / BN_, r = c - cb * BN_;
        int kc = k >> 3, j = k & 7;
        Wp[(size_t)cb * BN_ * K + ((size_t)kc * BN_ + r) * 8 + j] = (short)f2b(tile[kk][cc]);
    }
}

// ---------------- K=512 path: single-buffer BK=64 GEMM (packed, z-merged, BN=128) ----------------
__global__ __launch_bounds__(256) void gemm_mfma_kernel(
    const short* __restrict__ Xp, const short* __restrict__ Wp,
    unsigned short* __restrict__ O0, unsigned short* __restrict__ O1,
    unsigned short* __restrict__ O2, unsigned short* __restrict__ O3,
    int N, int K, int M) {
    const int BN_ = 128;
    // bijective XCD swizzle (m204)
    int nwg = gridDim.x;
    int wid = blockIdx.x;
    int qq = nwg >> 3, rr = nwg & 7;
    int xcd = wid & 7, li = wid >> 3;
    int swz = (xcd < rr ? xcd * (qq + 1) : rr * (qq + 1) + (xcd - rr) * qq) + li;
    int cols = (4 * M) / BN_;
    int row_blk = swz / cols;
    int cb = swz - row_blk * cols;
    int c0 = cb * BN_;
    int z = c0 / M;
    int m0 = c0 - z * M;
    unsigned short* O;
    switch (z) {
        case 0: O = O0; break;
        case 1: O = O1; break;
        case 2: O = O2; break;
        default: O = O3; break;
    }
    const short* Bp = Wp + (size_t)cb * BN_ * K;
    const short* Ap = Xp + (size_t)row_blk * 128 * K;

    __shared__ __align__(16) short As[8192];     // 8kc * 128 * 8 = 16 KB
    __shared__ __align__(16) short Bs[8192];     // 8kc * 128 * 8 = 16 KB

    int tid = threadIdx.x;
    int wave = tid >> 6, lane = tid & 63;
    int wrow = wave >> 1, wcol = wave & 1;
    int l15 = lane & 15, lk = lane >> 4;
    int row0 = row_blk * 128;

    f32x4 acc[4][4] = {};

    int nt = K >> 6;   // K/64
    for (int t = 0; t < nt; t++) {
#pragma unroll
        for (int i = 0; i < 4; i++) {
            __builtin_amdgcn_global_load_lds(
                (const __attribute__((address_space(1))) unsigned int*)(Ap + (size_t)t * 8192 + (size_t)(i * 256 + tid) * 8),
                (__attribute__((address_space(3))) unsigned int*)(As + (i * 256 + wave * 64) * 8),
                16, 0, 0);
            __builtin_amdgcn_global_load_lds(
                (const __attribute__((address_space(1))) unsigned int*)(Bp + (size_t)t * 8192 + (size_t)(i * 256 + tid) * 8),
                (__attribute__((address_space(3))) unsigned int*)(Bs + (i * 256 + wave * 64) * 8),
                16, 0, 0);
        }
        __syncthreads();

#pragma unroll 1
        for (int kh = 0; kh < 2; kh++) {
            int kc = kh * 4 + lk;
            bf16x8 a[4], b[4];
#pragma unroll
            for (int ii = 0; ii < 4; ii++)
                a[ii] = *(const bf16x8*)&As[kc * 1024 + (wrow * 64 + ii * 16 + l15) * 8];
#pragma unroll
            for (int j = 0; j < 4; j++)
                b[j] = *(const bf16x8*)&Bs[kc * 1024 + (wcol * 64 + j * 16 + l15) * 8];
#pragma unroll
            for (int ii = 0; ii < 4; ii++)
#pragma unroll
                for (int j = 0; j < 4; j++)
                    acc[ii][j] = __builtin_amdgcn_mfma_f32_16x16x32_bf16(a[ii], b[j], acc[ii][j], 0, 0, 0);
        }
        __syncthreads();
    }

#pragma unroll
    for (int ii = 0; ii < 4; ii++) {
#pragma unroll
        for (int r = 0; r < 4; r++) {
            int row = row0 + wrow * 64 + ii * 16 + lk * 4 + r;
            if (row < N) {
#pragma unroll
                for (int j = 0; j < 4; j++) {
                    O[(size_t)row * M + m0 + wcol * 64 + j * 16 + l15] = f2b(acc[ii][j][r]);
                }
            }
        }
    }
}

// ---------------- K=128 path: single-stage GEMM, NO K-loop (BN=128) ----------------
__global__ __launch_bounds__(256) void gemm_k128_kernel(
    const short* __restrict__ Xp, const short* __restrict__ Wp,
    unsigned short* __restrict__ O0, unsigned short* __restrict__ O1,
    unsigned short* __restrict__ O2, unsigned short* __restrict__ O3,
    int N, int M) {
    const int K = 128;
    const int BN_ = 128;
    int nwg = gridDim.x;
    int wid = blockIdx.x;
    int qq = nwg >> 3, rr = nwg & 7;
    int xcd = wid & 7, li = wid >> 3;
    int swz = (xcd < rr ? xcd * (qq + 1) : rr * (qq + 1) + (xcd - rr) * qq) + li;
    int cols = (4 * M) / BN_;
    int row_blk = swz / cols;
    int cb = swz - row_blk * cols;
    int c0 = cb * BN_;
    int z = c0 / M;
    int m0 = c0 - z * M;
    unsigned short* O;
    switch (z) {
        case 0: O = O0; break;
        case 1: O = O1; break;
        case 2: O = O2; break;
        default: O = O3; break;
    }
    const short* Bp = Wp + (size_t)cb * BN_ * K;
    const short* Ap = Xp + (size_t)row_blk * 128 * K;

    __shared__ __align__(16) short As[16384];
    __shared__ __align__(16) short Bs[16384];

    int tid = threadIdx.x;
    int wave = tid >> 6, lane = tid & 63;
    int wrow = wave >> 1, wcol = wave & 1;
    int l15 = lane & 15, lk = lane >> 4;
    int row0 = row_blk * 128;

#pragma unroll
    for (int i = 0; i < 8; i++) {
        __builtin_amdgcn_global_load_lds(
            (const __attribute__((address_space(1))) unsigned int*)(Ap + (size_t)(i * 256 + tid) * 8),
            (__attribute__((address_space(3))) unsigned int*)(As + (i * 256 + wave * 64) * 8),
            16, 0, 0);
        __builtin_amdgcn_global_load_lds(
            (const __attribute__((address_space(1))) unsigned int*)(Bp + (size_t)(i * 256 + tid) * 8),
            (__attribute__((address_space(3))) unsigned int*)(Bs + (i * 256 + wave * 64) * 8),
            16, 0, 0);
    }
    __syncthreads();

    f32x4 acc[4][4] = {};
#pragma unroll 1
    for (int kg = 0; kg < 4; kg++) {
        int kc = kg * 4 + lk;
        bf16x8 a[4], b[4];
#pragma unroll
        for (int ii = 0; ii < 4; ii++)
            a[ii] = *(const bf16x8*)&As[kc * 1024 + (wrow * 64 + ii * 16 + l15) * 8];
#pragma unroll
        for (int j = 0; j < 4; j++)
            b[j] = *(const bf16x8*)&Bs[kc * 1024 + (wcol * 64 + j * 16 + l15) * 8];
#pragma unroll
        for (int ii = 0; ii < 4; ii++)
#pragma unroll
            for (int j = 0; j < 4; j++)
                acc[ii][j] = __builtin_amdgcn_mfma_f32_16x16x32_bf16(a[ii], b[j], acc[ii][j], 0, 0, 0);
    }

#pragma unroll
    for (int ii = 0; ii < 4; ii++) {
#pragma unroll
        for (int r = 0; r < 4; r++) {
            int row = row0 + wrow * 64 + ii * 16 + lk * 4 + r;
            if (row < N) {
#pragma unroll
                for (int j = 0; j < 4; j++) {
                    O[(size_t)row * M + m0 + wcol * 64 + j * 16 + l15] = f2b(acc[ii][j][r]);
                }
            }
        }
    }
}

// ---------------- edge aggregation: 4 waves/node, BATCHED-4 gathers ----------------
template <int D>
__global__ __launch_bounds__(256) void edge_agg_kernel(
    const unsigned short* __restrict__ k, const unsigned short* __restrict__ q,
    const unsigned short* __restrict__ v, const unsigned short* __restrict__ s,
    const float* __restrict__ bias,
    const int* __restrict__ offs, const int* __restrict__ csr_src,
    float* __restrict__ y) {
    constexpr int FPL = D / 64;
    int i = blockIdx.x;
    int wv = threadIdx.x >> 6, lane = threadIdx.x & 63;
    int f0 = lane * FPL;
    size_t base = (size_t)i * D;

    float kf[FPL];
    if constexpr (FPL == 8) {
        bf16x8 kk = *(const bf16x8*)(k + base + f0);
#pragma unroll
        for (int w = 0; w < 8; w++) kf[w] = b2f((unsigned short)kk[w]);
    } else {
        unsigned ku = *(const unsigned*)(k + base + f0);
        kf[0] = __uint_as_float(ku << 16);
        kf[1] = __uint_as_float(ku & 0xFFFF0000u);
    }

    float acc[FPL] = {};
    int e0 = offs[i], e1 = offs[i + 1];
    int cnt = e1 - e0;
    int per = (cnt + 3) >> 2;
    int es = e0 + wv * per;
    int ee = min(es + per, e1);

    for (int e = es; e < ee; e += 4) {
        int n = ee - e;
        if (n > 4) n = 4;
        int js[4];
#pragma unroll
        for (int u = 0; u < 4; u++) js[u] = csr_src[(u < n) ? (e + u) : e];
        if constexpr (FPL == 8) {
            bf16x8 qv[4], vv[4];
#pragma unroll
            for (int u = 0; u < 4; u++) {
                size_t jb = (size_t)js[u] * D + f0;
                qv[u] = *(const bf16x8*)(q + jb);
                vv[u] = *(const bf16x8*)(v + jb);
            }
#pragma unroll
            for (int u = 0; u < 4; u++) {
                if (u < n) {
#pragma unroll
                    for (int w = 0; w < 8; w++)
                        acc[w] += sigmoid_fast(kf[w] + b2f((unsigned short)qv[u][w])) *
                                  b2f((unsigned short)vv[u][w]);
                }
            }
        } else {
            unsigned qv[4], vv[4];
#pragma unroll
            for (int u = 0; u < 4; u++) {
                size_t jb = (size_t)js[u] * D + f0;
                qv[u] = *(const unsigned*)(q + jb);
                vv[u] = *(const unsigned*)(v + jb);
            }
#pragma unroll
            for (int u = 0; u < 4; u++) {
                if (u < n) {
                    acc[0] += sigmoid_fast(kf[0] + __uint_as_float(qv[u] << 16)) *
                              __uint_as_float(vv[u] << 16);
                    acc[1] += sigmoid_fast(kf[1] + __uint_as_float(qv[u] & 0xFFFF0000u)) *
                              __uint_as_float(vv[u] & 0xFFFF0000u);
                }
            }
        }
    }

    __shared__ float red[3][D];
    if (wv > 0) {
#pragma unroll
        for (int w = 0; w < FPL; w++) red[wv - 1][f0 + w] = acc[w];
    }
    __syncthreads();
    if (wv == 0) {
        if constexpr (FPL == 8) {
            bf16x8 ssv = *(const bf16x8*)(s + base + f0);
#pragma unroll
            for (int w = 0; w < 8; w++) {
                float o = acc[w] + red[0][f0 + w] + red[1][f0 + w] + red[2][f0 + w] +
                          b2f((unsigned short)ssv[w]) + bias[f0 + w];
                y[base + f0 + w] = o > 0.f ? o : 0.f;
            }
        } else {
            unsigned su = *(const unsigned*)(s + base + f0);
            float2 bv = *(const float2*)(bias + f0);
            float ox = acc[0] + red[0][f0] + red[1][f0] + red[2][f0] +
                       __uint_as_float(su << 16) + bv.x;
            float oy = acc[1] + red[0][f0 + 1] + red[1][f0 + 1] + red[2][f0 + 1] +
                       __uint_as_float(su & 0xFFFF0000u) + bv.y;
            float2 o;
            o.x = ox > 0.f ? ox : 0.f;
            o.y = oy > 0.f ? oy : 0.f;
            *(float2*)(y + base + f0) = o;
        }
    }
}

// ---------------- batchnorm statistics (f32 input) ----------------
__global__ void col_stats_kernel(const float* __restrict__ y, int N, int D,
                                 float* __restrict__ sums, float* __restrict__ sumsq) {
    int f = blockIdx.x * 64 + (threadIdx.x & 63);
    int r0 = threadIdx.x >> 6;
    int rows_per = (N + gridDim.y - 1) / gridDim.y;
    int rs = blockIdx.y * rows_per;
    int re = min(rs + rows_per, N);
    float s = 0.f, s2 = 0.f;
    for (int r = rs + r0; r < re; r += 4) {
        float vv = y[(size_t)r * D + f];
        s += vv;
        s2 += vv * vv;
    }
    __shared__ float ls[2][256];
    ls[0][threadIdx.x] = s;
    ls[1][threadIdx.x] = s2;
    __syncthreads();
    if (threadIdx.x < 64) {
        float a = ls[0][threadIdx.x] + ls[0][threadIdx.x + 64] + ls[0][threadIdx.x + 128] + ls[0][threadIdx.x + 192];
        float b = ls[1][threadIdx.x] + ls[1][threadIdx.x + 64] + ls[1][threadIdx.x + 128] + ls[1][threadIdx.x + 192];
        atomicAdd(&sums[f], a);
        atomicAdd(&sumsq[f], b);
    }
}

// ---------------- batchnorm normalize + cast + PACK to next layer's A layout ----------------
__global__ void bn_norm_pack_kernel(const float* __restrict__ y, const float* __restrict__ sums,
                                    const float* __restrict__ sumsq, const float* __restrict__ g,
                                    const float* __restrict__ be, short* __restrict__ Xp,
                                    int N, int D, float inv_n) {
    int rb = blockIdx.x, t = blockIdx.y;
    size_t base = (size_t)rb * 128 * D + (size_t)t * 8192;
#pragma unroll
    for (int i = 0; i < 4; i++) {
        int c = i * 256 + threadIdx.x;
        int r = c >> 3, kc = c & 7;
        int row = rb * 128 + r;
        int f = t * 64 + kc * 8;
        float v[8] = {};
        if (row < N) {
            float4 a = *(const float4*)(y + (size_t)row * D + f);
            float4 b = *(const float4*)(y + (size_t)row * D + f + 4);
            v[0] = a.x; v[1] = a.y; v[2] = a.z; v[3] = a.w;
            v[4] = b.x; v[5] = b.y; v[6] = b.z; v[7] = b.w;
        }
        float4 sm0 = *(const float4*)(sums + f), sm1 = *(const float4*)(sums + f + 4);
        float4 sq0 = *(const float4*)(sumsq + f), sq1 = *(const float4*)(sumsq + f + 4);
        float4 g0 = *(const float4*)(g + f), g1 = *(const float4*)(g + f + 4);
        float4 b0 = *(const float4*)(be + f), b1 = *(const float4*)(be + f + 4);
        float sm[8] = {sm0.x, sm0.y, sm0.z, sm0.w, sm1.x, sm1.y, sm1.z, sm1.w};
        float sq[8] = {sq0.x, sq0.y, sq0.z, sq0.w, sq1.x, sq1.y, sq1.z, sq1.w};
        float gg[8] = {g0.x, g0.y, g0.z, g0.w, g1.x, g1.y, g1.z, g1.w};
        float bb[8] = {b0.x, b0.y, b0.z, b0.w, b1.x, b1.y, b1.z, b1.w};
        bf16x8 o;
#pragma unroll
        for (int j = 0; j < 8; j++) {
            float mu = sm[j] * inv_n;
            float var = sq[j] * inv_n - mu * mu;
            float val = (v[j] - mu) * rsqrtf(var + EPS) * gg[j] + bb[j];
            o[j] = (short)f2b(val);
        }
        *(bf16x8*)(Xp + base + ((size_t)kc * 128 + r) * 8) = o;
    }
}

// ---------------- last-layer batchnorm normalize fused with global add pool (f32 y) ----------------
__global__ void bn_norm_pool_kernel(const float* __restrict__ y, const float* __restrict__ sums,
                                    const float* __restrict__ sumsq, const float* __restrict__ g,
                                    const float* __restrict__ be, const int* __restrict__ batch,
                                    float* __restrict__ out, int N, int D) {
    int idx = blockIdx.x * blockDim.x + threadIdx.x;
    int total = N * D;
    float inv_n = 1.f / (float)N;
    if (idx < total) {
        int f = idx & (D - 1);
        int i = idx >> 7;  // D == 128
        float mu = sums[f] * inv_n;
        float var = sumsq[f] * inv_n - mu * mu;
        float inv = rsqrtf(var + EPS);
        float val = (y[idx] - mu) * inv * g[f] + be[f];
        atomicAdd(&out[batch[i] * D + f], val);
    }
}

extern "C" void kernel_launch(void* const* d_in, const int* in_sizes, int n_in,
                              void* d_out, int out_size, void* d_ws, size_t ws_size,
                              hipStream_t stream) {
    const float* x_in = (const float*)d_in[0];
    const int* eidx = (const int*)d_in[1];
    const int* batch = (const int*)d_in[2];
    const int N = N_NODES;
    const int E = N_EDGES;
    const int* src = eidx;
    const int* dstp = eidx + E;

    const float *Wk[5], *Wq[5], *Wv[5], *Ws[5], *bb[5], *gg[5], *bebe[5];
    for (int l = 0; l < 5; l++) {
        Wk[l]   = (const float*)d_in[3 + l * 7 + 0];
        Wq[l]   = (const float*)d_in[3 + l * 7 + 1];
        Wv[l]   = (const float*)d_in[3 + l * 7 + 2];
        Ws[l]   = (const float*)d_in[3 + l * 7 + 3];
        bb[l]   = (const float*)d_in[3 + l * 7 + 4];
        gg[l]   = (const float*)d_in[3 + l * 7 + 5];
        bebe[l] = (const float*)d_in[3 + l * 7 + 6];
    }
    const int dims_in[5]  = {128, 512, 512, 128, 128};
    const int dims_out[5] = {512, 512, 128, 128, 128};

    // ---- workspace carve ----
    char* w = (char*)d_ws;
    const size_t SZH = (size_t)N * 512 * sizeof(short);
    unsigned short* kb16 = (unsigned short*)w; w += SZH;
    unsigned short* qb16 = (unsigned short*)w; w += SZH;
    unsigned short* vb16 = (unsigned short*)w; w += SZH;
    unsigned short* sb16 = (unsigned short*)w; w += SZH;
    float* yb = (float*)w;                     w += (size_t)N * 512 * sizeof(float);
    short* Xp = (short*)w;                     w += (size_t)N_PAD * 512 * sizeof(short);
    float* bnbuf = (float*)w;                  w += 5 * 1024 * sizeof(float);
    int* counts = (int*)w;
    int* offs = counts + 10016;
    int* pos = offs + 10016;
    int* csr = pos + 10016;
    w += (3 * 10016 + N_EDGES) * sizeof(int);
    w = (char*)(((uintptr_t)w + 255) & ~(uintptr_t)255);
    short* Wp[5];
    for (int l = 0; l < 5; l++) {
        Wp[l] = (short*)w;
        w += (size_t)4 * dims_out[l] * dims_in[l] * sizeof(short);
    }

    hipMemsetAsync(counts, 0, (size_t)N * sizeof(int), stream);
    hipMemsetAsync(bnbuf, 0, 5 * 1024 * sizeof(float), stream);
    hipMemsetAsync(d_out, 0, (size_t)out_size * sizeof(float), stream);

    hist_kernel<<<(E + 255) / 256, 256, 0, stream>>>(dstp, counts, E);
    scan_kernel<<<1, 1024, 0, stream>>>(counts, offs, pos, N);
    scatter_kernel<<<(E + 255) / 256, 256, 0, stream>>>(src, dstp, pos, csr, E);

    cast_x_pack_kernel<<<dim3(N_PAD / 128, 128 / 64), 256, 0, stream>>>(x_in, Xp, N, 128);
    for (int l = 0; l < 5; l++) {
        int K = dims_in[l], M = dims_out[l];
        dim3 pg((4 * M) / 32, K / 32);
        pack_w_kernel<<<pg, dim3(32, 8), 0, stream>>>(
            Wk[l], Wq[l], Wv[l], Ws[l], Wp[l], K, M);
    }

    for (int l = 0; l < 5; l++) {
        int K = dims_in[l], M = dims_out[l];
        float* bnsum = bnbuf + l * 1024;
        float* bnsq = bnsum + 512;
        int nwg = (N_PAD / 128) * ((4 * M) / 128);
        if (K == 512) {
            gemm_mfma_kernel<<<nwg, 256, 0, stream>>>(
                Xp, Wp[l], kb16, qb16, vb16, sb16, N, K, M);
        } else {
            gemm_k128_kernel<<<nwg, 256, 0, stream>>>(
                Xp, Wp[l], kb16, qb16, vb16, sb16, N, M);
        }
        if (M == 512)
            edge_agg_kernel<512><<<N, 256, 0, stream>>>(kb16, qb16, vb16, sb16, bb[l], offs, csr, yb);
        else
            edge_agg_kernel<128><<<N, 256, 0, stream>>>(kb16, qb16, vb16, sb16, bb[l], offs, csr, yb);
        dim3 gs(M / 64, 79);
        col_stats_kernel<<<gs, 256, 0, stream>>>(yb, N, M, bnsum, bnsq);
        if (l == 4)
            bn_norm_pool_kernel<<<(N * M + 255) / 256, 256, 0, stream>>>(
                yb, bnsum, bnsq, gg[l], bebe[l], batch, (float*)d_out, N, M);
        else
            bn_norm_pack_kernel<<<dim3(N_PAD / 128, M / 64), 256, 0, stream>>>(
                yb, bnsum, bnsq, gg[l], bebe[l], Xp, N, M, 1.f / (float)N);
    }
}